// Round 13
// baseline (352.293 us; speedup 1.0000x reference)
//
#include <hip/hip_runtime.h>
#include <cstdint>

typedef unsigned short u16;
typedef __attribute__((ext_vector_type(8))) short s16x8;
typedef __attribute__((ext_vector_type(4))) float f32x4;

#define NTOK 4096
#define DH   64
#define DM   1024
#define NH   16

static __device__ __forceinline__ float b2f(u16 u){ return __uint_as_float(((unsigned)u)<<16); }
static __device__ __forceinline__ u16 f2b(float f){
  unsigned u = __float_as_uint(f);
  return (u16)((u + 0x7FFFu + ((u>>16)&1u)) >> 16);   // RNE
}

static __device__ __forceinline__ void gload_lds16(const void* g, void* l) {
  __builtin_amdgcn_global_load_lds(
      (const __attribute__((address_space(1))) unsigned*)(uintptr_t)g,
      (__attribute__((address_space(3))) unsigned*)(uintptr_t)l, 16, 0, 0);
}

static __device__ __forceinline__ s16x8 ld8(const u16* p){ return *(const s16x8*)(const void*)p; }

// ---------------- merged pre-pass: cvt_xl (1024 blks) | cvt_t Wqkv (768) | cvt_t Wout (256) ----------------
__global__ __launch_bounds__(256) void k_pre(const float* __restrict__ hs, u16* __restrict__ Xb,
                                             float* __restrict__ Xl,
                                             const float* __restrict__ Wqkv, u16* __restrict__ WqkvT,
                                             const float* __restrict__ Wout, u16* __restrict__ WoutT) {
  __shared__ float tile[64][65];
  const int bid = blockIdx.x, t = threadIdx.x;
  if (bid < 1024) {
    const int grp = bid >> 2;
    const int d = (bid & 3)*256 + t;
    const float* p = hs + (long)grp*64*DM + d;
    u16* xo = Xb + (long)grp*64*DM + d;
    float s = 0.f;
    #pragma unroll 8
    for (int i = 0; i < 64; ++i) {
      const float v = p[(long)i*DM];
      s += v;
      xo[(long)i*DM] = f2b(v);
    }
    Xl[(long)grp*DM + d] = s * (1.0f/64.0f);
    return;
  }
  const float* in; u16* out; int R, C, tc, tr;
  if (bid < 1792) { const int x = bid - 1024; in = Wqkv; out = WqkvT; R = 1024; C = 3072; tc = x % 48; tr = x / 48; }
  else            { const int x = bid - 1792; in = Wout; out = WoutT; R = 1024; C = 1024; tc = x & 15;  tr = x >> 4; }
  const int cx = t & 63, ry = t >> 6;
  #pragma unroll
  for (int p = 0; p < 16; ++p) {
    const int row = p*4 + ry;
    tile[row][cx] = in[(long)(tr*64 + row)*C + tc*64 + cx];
  }
  __syncthreads();
  #pragma unroll
  for (int p = 0; p < 16; ++p) {
    const int orow = p*4 + ry;
    out[(long)(tc*64 + orow)*R + tr*64 + cx] = f2b(tile[cx][orow]);
  }
}

// ---------------- fp32 projection, K-split: psum[z][row][col] partials ----------------
__global__ __launch_bounds__(256) void k_lproj2(const float* __restrict__ Xl, const float* __restrict__ Wqkv,
                                                float* __restrict__ psum) {
  __shared__ __align__(16) float Xs[32][68];
  const int t = threadIdx.x;
  const int wcol = blockIdx.x*256 + t;    // 0..2047
  const int r0 = blockIdx.y*32;
  const int kbase = blockIdx.z*128;
  float acc[32];
  #pragma unroll
  for (int r = 0; r < 32; ++r) acc[r] = 0.f;
  for (int k0 = kbase; k0 < kbase + 128; k0 += 64) {
    __syncthreads();
    for (int idx = t; idx < 2048; idx += 256)
      Xs[idx>>6][idx&63] = Xl[(long)(r0 + (idx>>6))*DM + k0 + (idx&63)];
    __syncthreads();
    for (int kk = 0; kk < 64; kk += 4) {
      f32x4 wv;
      #pragma unroll
      for (int j = 0; j < 4; ++j) wv[j] = Wqkv[(long)(k0+kk+j)*3072 + wcol];
      #pragma unroll
      for (int r = 0; r < 32; ++r) {
        const f32x4 xv = *(const f32x4*)&Xs[r][kk];
        acc[r] += xv[0]*wv[0] + xv[1]*wv[1] + xv[2]*wv[2] + xv[3]*wv[3];
      }
    }
  }
  float* po = psum + ((long)blockIdx.z*256 + r0)*2048 + wcol;
  #pragma unroll
  for (int r = 0; r < 32; ++r) po[(long)r*2048] = acc[r];
}

// ---------------- reduce K-slices + bias + scale -> qlf/klf/qlb/klb ----------------
__global__ __launch_bounds__(256) void k_lreduce(const float* __restrict__ psum, const float* __restrict__ bqkv,
                                                 float* __restrict__ qlf, float* __restrict__ klf,
                                                 u16* __restrict__ qlb, u16* __restrict__ klb) {
  const long idx = (long)blockIdx.x*256 + threadIdx.x;
  const int row = (int)(idx >> 11), col = (int)(idx & 2047);
  float s = 0.f;
  #pragma unroll
  for (int z = 0; z < 8; ++z) s += psum[((long)z*256 + row)*2048 + col];
  const int isq = (col < 1024) ? 1 : 0;
  float val = s + bqkv[col];
  if (isq) val *= 0.125f;
  const int b = row >> 6, lm = row & 63;
  const int c2 = col & 1023, h = c2 >> 6, dh = c2 & 63;
  const long o = (((long)b*NH + h)*64 + lm)*64 + dh;
  if (isq) { qlf[o] = val; qlb[o] = f2b(val); }
  else     { klf[o] = val; klb[o] = f2b(val); }
}

// ---------------- GEMM 256x256, BK=64, 8 waves, 2x64KB dbuf, 8-phase schedule (r12, kept) ----------------
template<int EPI>
__global__ __launch_bounds__(512, 2) void k_gemm256(
    const u16* __restrict__ A, const u16* __restrict__ Bt, const float* __restrict__ bias,
    int N, float* __restrict__ outF, u16* __restrict__ outQ, u16* __restrict__ outK, u16* __restrict__ outV)
{
  __shared__ __align__(16) u16 lds[2*32768];
  const int t = threadIdx.x;
  const int lane = t & 63;
  const int wid = t >> 6;
  const int c = lane & 15, g = lane >> 4;
  const int wm = wid >> 2, wn = wid & 3;
  const int fid = blockIdx.y*64 + blockIdx.x;
  const int nbx = ((fid & 7) << 3) | ((fid >> 3) & 7);
  const int nby = fid >> 6;
  const long arow0 = (long)nbx * 256;
  const long brow0 = (long)nby * 256;
  char* ldsb = (char*)lds;

  const int srow3 = t >> 3;
  const int sch = ((t & 7) ^ (srow3 & 7)) * 8;
  const u16* sA = A  + (arow0 + srow3)*1024 + sch;
  const u16* sB = Bt + (brow0 + srow3)*1024 + sch;
  const int dbase = t*16;

#define STG(gp, R0, Toff, kbe, nb) { \
    char* d0 = ldsb + (nb)*65536 + (Toff) + (R0)*128 + dbase; \
    gload_lds16((gp) + (long)(R0)*1024 + (kbe), d0); \
    gload_lds16((gp) + (long)((R0)+64)*1024 + (kbe), d0 + 8192); }

  const int cp0 = ((g     ) ^ (c & 7)) * 16;
  const int cp1 = ((4 | g ) ^ (c & 7)) * 16;
  int rowA[4], rowB[4];
  #pragma unroll
  for (int mi = 0; mi < 4; ++mi) {
    rowA[mi] = (wm*64 + mi*16 + c)*128;
    rowB[mi] = 32768 + (wn*64 + mi*16 + c)*128;
  }

  f32x4 acc0[4][4] = {};
  f32x4 acc1[4][4] = {};

  STG(sB, 0, 32768, 0, 0)
  STG(sB, 128, 32768, 0, 0)
  STG(sA, 0, 0, 0, 0)
  STG(sA, 128, 0, 0, 0)
  asm volatile("s_waitcnt vmcnt(2)" ::: "memory");
  __builtin_amdgcn_s_barrier();

  for (int it = 0; it < 16; ++it) {
    char* buf = ldsb + (it&1)*65536;
    const int nb = (it+1)&1;
    const int kb1 = (it+1)*64;
    const bool last = (it == 15);
    s16x8 fa[4], fb[4], ga[4];
    // ---- P0 ----
    #pragma unroll
    for (int mi = 0; mi < 4; ++mi) fa[mi] = *(const s16x8*)(buf + rowA[mi] + cp0);
    #pragma unroll
    for (int ni = 0; ni < 4; ++ni) fb[ni] = *(const s16x8*)(buf + rowB[ni] + cp0);
    if (!last) STG(sB, 0, 32768, kb1, nb)
    __builtin_amdgcn_s_barrier();
    asm volatile("s_waitcnt lgkmcnt(0)" ::: "memory");
    __builtin_amdgcn_sched_barrier(0);
    __builtin_amdgcn_s_setprio(1);
    #pragma unroll
    for (int mi = 0; mi < 4; ++mi)
      #pragma unroll
      for (int ni = 0; ni < 4; ++ni)
        acc0[mi][ni] = __builtin_amdgcn_mfma_f32_16x16x32_bf16(fa[mi], fb[ni], acc0[mi][ni], 0, 0, 0);
    __builtin_amdgcn_s_setprio(0);
    if (last) { asm volatile("s_waitcnt vmcnt(0)" ::: "memory"); }
    else      { asm volatile("s_waitcnt vmcnt(2)" ::: "memory"); }
    __builtin_amdgcn_s_barrier();
    // ---- P1 ----
    #pragma unroll
    for (int mi = 0; mi < 4; ++mi) ga[mi] = *(const s16x8*)(buf + rowA[mi] + 16384 + cp0);
    if (!last) STG(sB, 128, 32768, kb1, nb)
    __builtin_amdgcn_s_barrier();
    asm volatile("s_waitcnt lgkmcnt(0)" ::: "memory");
    __builtin_amdgcn_sched_barrier(0);
    __builtin_amdgcn_s_setprio(1);
    #pragma unroll
    for (int mi = 0; mi < 4; ++mi)
      #pragma unroll
      for (int ni = 0; ni < 4; ++ni)
        acc1[mi][ni] = __builtin_amdgcn_mfma_f32_16x16x32_bf16(ga[mi], fb[ni], acc1[mi][ni], 0, 0, 0);
    __builtin_amdgcn_s_setprio(0);
    __builtin_amdgcn_s_barrier();
    // ---- P2 ----
    #pragma unroll
    for (int mi = 0; mi < 4; ++mi) fa[mi] = *(const s16x8*)(buf + rowA[mi] + cp1);
    #pragma unroll
    for (int ni = 0; ni < 4; ++ni) fb[ni] = *(const s16x8*)(buf + rowB[ni] + cp1);
    if (!last) STG(sA, 0, 0, kb1, nb)
    __builtin_amdgcn_s_barrier();
    asm volatile("s_waitcnt lgkmcnt(0)" ::: "memory");
    __builtin_amdgcn_sched_barrier(0);
    __builtin_amdgcn_s_setprio(1);
    #pragma unroll
    for (int mi = 0; mi < 4; ++mi)
      #pragma unroll
      for (int ni = 0; ni < 4; ++ni)
        acc0[mi][ni] = __builtin_amdgcn_mfma_f32_16x16x32_bf16(fa[mi], fb[ni], acc0[mi][ni], 0, 0, 0);
    __builtin_amdgcn_s_setprio(0);
    __builtin_amdgcn_s_barrier();
    // ---- P3 ----
    #pragma unroll
    for (int mi = 0; mi < 4; ++mi) ga[mi] = *(const s16x8*)(buf + rowA[mi] + 16384 + cp1);
    if (!last) STG(sA, 128, 0, kb1, nb)
    __builtin_amdgcn_s_barrier();
    asm volatile("s_waitcnt lgkmcnt(0)" ::: "memory");
    __builtin_amdgcn_sched_barrier(0);
    __builtin_amdgcn_s_setprio(1);
    #pragma unroll
    for (int mi = 0; mi < 4; ++mi)
      #pragma unroll
      for (int ni = 0; ni < 4; ++ni)
        acc1[mi][ni] = __builtin_amdgcn_mfma_f32_16x16x32_bf16(ga[mi], fb[ni], acc1[mi][ni], 0, 0, 0);
    __builtin_amdgcn_s_setprio(0);
    if (!last) { asm volatile("s_waitcnt vmcnt(2)" ::: "memory"); }
    __builtin_amdgcn_s_barrier();
  }
#undef STG

  if (EPI == 0) {
    const int tensor = (int)(brow0 >> 10);
    if (tensor == 2) {
      __syncthreads();
      u16* wlds = lds + wid*4224;
      const int hbase = (int)((brow0 + wn*64) & 1023);
      const int head = hbase >> 6;
      #pragma unroll
      for (int ph = 0; ph < 2; ++ph) {
        const long grow0 = arow0 + ph*128 + wm*64;
        const int b = (int)(grow0 >> 12), tok0r = (int)(grow0 & 4095);
        #pragma unroll
        for (int mi = 0; mi < 4; ++mi)
          #pragma unroll
          for (int ni = 0; ni < 4; ++ni) {
            const float bv = bias[brow0 + wn*64 + ni*16 + c];
            const f32x4 a = ph ? acc1[mi][ni] : acc0[mi][ni];
            #pragma unroll
            for (int r = 0; r < 4; ++r)
              wlds[(mi*16 + g*4 + r)*66 + ni*16 + c] = f2b(a[r] + bv);
          }
        asm volatile("s_waitcnt lgkmcnt(0)" ::: "memory");
        u16* vbase = outV + (((long)b*NH + head)*DH)*NTOK + tok0r;
        #pragma unroll
        for (int j = 0; j < 8; ++j) {
          const int d = j*8 + (lane >> 3);
          const int tk = (lane & 7)*8;
          s16x8 vv;
          #pragma unroll
          for (int s2 = 0; s2 < 8; ++s2) vv[s2] = (short)wlds[(tk + s2)*66 + d];
          *(s16x8*)(vbase + (long)d*NTOK + tk) = vv;
        }
        asm volatile("s_waitcnt lgkmcnt(0)" ::: "memory");
      }
    } else {
      u16* dst = (tensor == 0) ? outQ : outK;
      const float mul = (tensor == 0) ? 0.125f : 1.0f;
      #pragma unroll
      for (int ph = 0; ph < 2; ++ph)
        #pragma unroll
        for (int mi = 0; mi < 4; ++mi) {
          const int rowb = ph*128 + wm*64 + mi*16 + g*4;
          #pragma unroll
          for (int ni = 0; ni < 4; ++ni) {
            const long gcol = brow0 + wn*64 + ni*16 + c;
            const int c2 = (int)(gcol & 1023);
            const int head = c2 >> 6, dh = c2 & 63;
            const float bv = bias[gcol];
            const f32x4 a = ph ? acc1[mi][ni] : acc0[mi][ni];
            #pragma unroll
            for (int r = 0; r < 4; ++r) {
              const long grow = arow0 + rowb + r;
              const int b = (int)(grow >> 12), tok = (int)(grow & 4095);
              dst[(((long)b*NH + head)*NTOK + tok)*DH + dh] = f2b((a[r] + bv)*mul);
            }
          }
        }
    }
  } else {
    #pragma unroll
    for (int ph = 0; ph < 2; ++ph)
      #pragma unroll
      for (int mi = 0; mi < 4; ++mi) {
        const int rowb = ph*128 + wm*64 + mi*16 + g*4;
        #pragma unroll
        for (int ni = 0; ni < 4; ++ni) {
          const long gcol = brow0 + wn*64 + ni*16 + c;
          const float bv = bias[gcol];
          const f32x4 a = ph ? acc1[mi][ni] : acc0[mi][ni];
          #pragma unroll
          for (int r = 0; r < 4; ++r) {
            const long grow = arow0 + rowb + r;
            outF[grow*N + gcol] = a[r] + bv;
          }
        }
      }
  }
}

// ---------------- fp32 LDS 64x64 matmul helpers ----------------
#define PST 68
static __device__ __forceinline__ void mm_nn4(const float* A, const float* B, float* C, int t) {
  const int lane = t & 63, j0 = (t >> 6) << 2;
  float acc[4] = {0.f, 0.f, 0.f, 0.f};
  for (int k = 0; k < 64; k += 4) {
    const f32x4 a4 = *(const f32x4*)&A[lane*PST + k];
    #pragma unroll
    for (int dk = 0; dk < 4; ++dk) {
      const f32x4 b0 = *(const f32x4*)&B[(k + dk)*PST + j0];
      #pragma unroll
      for (int q = 0; q < 4; ++q) acc[q] += a4[dk]*b0[q];
    }
  }
  #pragma unroll
  for (int j = 0; j < 4; ++j) C[lane*PST + j0 + j] = acc[j];
}
static __device__ __forceinline__ void mm_nt4(const float* A, const float* B, float* C, int t) {
  const int lane = t & 63, j0 = (t >> 6) << 2;
  float acc[4] = {0.f, 0.f, 0.f, 0.f};
  for (int k = 0; k < 64; k += 4) {
    const f32x4 a4 = *(const f32x4*)&A[lane*PST + k];
    #pragma unroll
    for (int jj = 0; jj < 4; ++jj) {
      const f32x4 b4 = *(const f32x4*)&B[(j0 + jj)*PST + k];
      acc[jj] += a4[0]*b4[0] + a4[1]*b4[1] + a4[2]*b4[2] + a4[3]*b4[3];
    }
  }
  #pragma unroll
  for (int j = 0; j < 4; ++j) C[lane*PST + j0 + j] = acc[j];
}

// ---------------- merged: pinv (blocks 0..63, 1024 thr) | attn3v partials (blocks 64..575) ----------------
// pinv at 1024 threads (mm_nn4: 4 cols/thread) halves the serial VALU chain vs 512 thr.
// attn3v computes with t<256; all 1024 threads join barriers and do the final reductions.
__global__ __launch_bounds__(1024) void k_pa(const float* __restrict__ qlf, const float* __restrict__ klf,
                                             float* __restrict__ a2inv,
                                             const u16* __restrict__ qlb, const u16* __restrict__ kk,
                                             const u16* __restrict__ vt,
                                             float* __restrict__ zp, float* __restrict__ sp) {
  __shared__ __align__(16) char smem[87040];
  const int t = threadIdx.x;
  if (blockIdx.x < 64) {
    float* Xb = (float*)smem;
    float* Vb = Xb + 64*PST;
    float* T1 = Vb + 64*PST;
    float* T2 = T1 + 64*PST;
    float* T3 = T2 + 64*PST;
    const int bh = blockIdx.x;
    const float* ql = qlf + (long)bh*4096;
    const float* kl = klf + (long)bh*4096;
    for (int i = t; i < 4096; i += 1024) { T1[(i>>6)*PST + (i&63)] = ql[i]; T2[(i>>6)*PST + (i&63)] = kl[i]; }
    __syncthreads();
    mm_nt4(T1, T2, Xb, t);
    __syncthreads();
    if (t < 64) {
      float mx = -1e30f;
      for (int j = 0; j < 64; ++j) mx = fmaxf(mx, Xb[t*PST + j]);
      float s = 0.f;
      for (int j = 0; j < 64; ++j) { const float e = expf(Xb[t*PST + j] - mx); Xb[t*PST + j] = e; s += e; }
      const float inv = 1.0f/s;
      for (int j = 0; j < 64; ++j) Xb[t*PST + j] *= inv;
    }
    __syncthreads();
    for (int i = t; i < 4096; i += 1024) { const int r = i>>6, cc = i&63; Vb[r*PST+cc] = Xb[r*PST+cc]; }
    __syncthreads();
    for (int it = 0; it < 6; ++it) {
      mm_nn4(Xb, Vb, T1, t);  __syncthreads();
      for (int i = t; i < 4096; i += 1024) { const int r=i>>6, cc=i&63; T2[r*PST+cc] = (r==cc?7.0f:0.0f) - T1[r*PST+cc]; }
      __syncthreads();
      mm_nn4(T1, T2, T3, t);  __syncthreads();
      for (int i = t; i < 4096; i += 1024) { const int r=i>>6, cc=i&63; T2[r*PST+cc] = (r==cc?15.0f:0.0f) - T3[r*PST+cc]; }
      __syncthreads();
      mm_nn4(T1, T2, T3, t);  __syncthreads();
      for (int i = t; i < 4096; i += 1024) { const int r=i>>6, cc=i&63; T2[r*PST+cc] = (r==cc?13.0f:0.0f) - T3[r*PST+cc]; }
      __syncthreads();
      mm_nn4(Vb, T2, T3, t);  __syncthreads();
      for (int i = t; i < 4096; i += 1024) { const int r=i>>6, cc=i&63; Vb[r*PST+cc] = 0.25f*T3[r*PST+cc]; }
      __syncthreads();
    }
    for (int i = t; i < 4096; i += 1024) a2inv[(long)bh*4096 + i] = Vb[(i>>6)*PST + (i&63)];
    return;
  }
  float* Zlp = (float*)smem;               // [4][64][64]
  float* Slp = (float*)(smem + 65536);     // [4][64]
  char*  Plb = smem + 66560;               // [4][64][80B]
  const int abid = blockIdx.x - 64;
  const int bh = abid >> 3, qt = abid & 7;
  if (t < 256) {
    const int w = t >> 6, lane = t & 63;
    const int c = lane & 15, g = lane >> 4;
    s16x8 aq[4][2];
    const u16* qlp = qlb + (long)bh*4096;
    #pragma unroll
    for (int mi = 0; mi < 4; ++mi)
      #pragma unroll
      for (int ks = 0; ks < 2; ++ks)
        aq[mi][ks] = ld8(qlp + (mi*16 + c)*64 + ks*32 + g*8);

    f32x4 zacc[4][4] = {};
    float sl[4][4] = {};
    const u16* kp = kk + (long)bh*NTOK*DH;
    const u16* vp = vt + (long)bh*DH*NTOK;
    char* pbase = Plb + w*5120;
    const int tok00 = qt*512 + w*128;

    for (int it = 0; it < 4; ++it) {
      const int t0 = tok00 + it*32;
      f32x4 sacc[4][2] = {};
      s16x8 kb[2][2];
      #pragma unroll
      for (int cg = 0; cg < 2; ++cg)
        #pragma unroll
        for (int ks = 0; ks < 2; ++ks)
          kb[cg][ks] = ld8(kp + (long)(t0 + cg*16 + c)*64 + ks*32 + g*8);
      #pragma unroll
      for (int cg = 0; cg < 2; ++cg)
        #pragma unroll
        for (int ks = 0; ks < 2; ++ks)
          #pragma unroll
          for (int mi = 0; mi < 4; ++mi)
            sacc[mi][cg] = __builtin_amdgcn_mfma_f32_16x16x32_bf16(aq[mi][ks], kb[cg][ks], sacc[mi][cg], 0, 0, 0);
      #pragma unroll
      for (int mi = 0; mi < 4; ++mi)
        #pragma unroll
        for (int r = 0; r < 4; ++r) {
          const int row = mi*16 + g*4 + r;
          const float p0 = __expf(sacc[mi][0][r]);
          const float p1 = __expf(sacc[mi][1][r]);
          sl[mi][r] += p0 + p1;
          char* base = pbase + row*80;
          *(u16*)(base + c*2)      = f2b(p0);
          *(u16*)(base + 32 + c*2) = f2b(p1);
        }
      s16x8 pa[4];
      #pragma unroll
      for (int mi = 0; mi < 4; ++mi) pa[mi] = *(const s16x8*)(pbase + (mi*16 + c)*80 + g*16);
      #pragma unroll
      for (int ni = 0; ni < 4; ++ni) {
        const s16x8 vb = ld8(vp + (long)(ni*16 + c)*NTOK + t0 + g*8);
        #pragma unroll
        for (int mi = 0; mi < 4; ++mi)
          zacc[mi][ni] = __builtin_amdgcn_mfma_f32_16x16x32_bf16(pa[mi], vb, zacc[mi][ni], 0, 0, 0);
      }
    }
    #pragma unroll
    for (int mi = 0; mi < 4; ++mi)
      #pragma unroll
      for (int r = 0; r < 4; ++r) {
        float s = sl[mi][r];
        s += __shfl_xor(s, 1); s += __shfl_xor(s, 2); s += __shfl_xor(s, 4); s += __shfl_xor(s, 8);
        sl[mi][r] = s;
      }
    #pragma unroll
    for (int mi = 0; mi < 4; ++mi)
      #pragma unroll
      for (int ni = 0; ni < 4; ++ni)
        #pragma unroll
        for (int r = 0; r < 4; ++r)
          Zlp[w*4096 + (mi*16 + g*4 + r)*64 + ni*16 + c] = zacc[mi][ni][r];
    if (c == 0)
      #pragma unroll
      for (int mi = 0; mi < 4; ++mi)
        #pragma unroll
        for (int r = 0; r < 4; ++r)
          Slp[w*64 + mi*16 + g*4 + r] = sl[mi][r];
  }
  __syncthreads();
  float* zpp = zp + (long)abid*4096;
  for (int i = t; i < 4096; i += 1024)
    zpp[i] = Zlp[i] + Zlp[4096 + i] + Zlp[8192 + i] + Zlp[12288 + i];
  if (t < 64) sp[(long)abid*64 + t] = Slp[t] + Slp[64 + t] + Slp[128 + t] + Slp[192 + t];
}

// ---------------- fused: z-reduce + W2^T = (attn2inv @ z)^T  (bf16 [dh][lm], 1024 thr) ----------------
__global__ __launch_bounds__(1024) void k_w2(const float* __restrict__ a2inv,
                                             const float* __restrict__ zp, const float* __restrict__ sp,
                                             u16* __restrict__ w2t) {
  __shared__ __align__(16) float Ai[64*PST];
  __shared__ __align__(16) float Zi[64*PST];
  __shared__ __align__(16) float Ci[64*PST];
  __shared__ float Ss[64];
  const int bh = blockIdx.x, t = threadIdx.x;
  if (t < 64) {
    float ss = 0.f;
    #pragma unroll
    for (int qt = 0; qt < 8; ++qt) ss += sp[(long)(bh*8 + qt)*64 + t];
    Ss[t] = 1.0f / ss;
  }
  for (int i = t; i < 4096; i += 1024)
    Ai[(i>>6)*PST + (i&63)] = a2inv[(long)bh*4096 + i];
  __syncthreads();
  for (int i = t; i < 4096; i += 1024) {
    float zs = 0.f;
    #pragma unroll
    for (int qt = 0; qt < 8; ++qt) zs += zp[((long)(bh*8 + qt))*4096 + i];
    Zi[(i>>6)*PST + (i&63)] = zs * Ss[i>>6];
  }
  __syncthreads();
  mm_nn4(Ai, Zi, Ci, t);
  __syncthreads();
  for (int i = t; i < 4096; i += 1024) { const int r = i>>6, cc = i&63; w2t[(long)bh*4096 + cc*64 + r] = f2b(Ci[r*PST + cc]); }
}

// ---------------- out_h = softmax(q @ k_l^T) @ W2: 256 blocks, 4 token-tiles/block ----------------
#define P1ST 144
__global__ __launch_bounds__(256) void k_attn1(const u16* __restrict__ q, const u16* __restrict__ klb,
                                               const u16* __restrict__ w2t, u16* __restrict__ ao) {
  __shared__ __align__(16) u16 Pl[4][64][72];
  const int bx = blockIdx.x, bh = bx >> 2, qd = bx & 3;
  const int b = bh >> 4, h = bh & 15;
  const int t = threadIdx.x, w = t >> 6, lane = t & 63;
  const int c = lane & 15, g = lane >> 4;
  const u16* klp = klb + (long)bh*4096;
  const u16* wp  = w2t + (long)bh*4096;
  char* pbase = (char*)&Pl[w][0][0];

  s16x8 kb[4][2], wb[4][2];
  #pragma unroll
  for (int i = 0; i < 4; ++i)
    #pragma unroll
    for (int ks = 0; ks < 2; ++ks) {
      kb[i][ks] = ld8(klp + (i*16 + c)*64 + ks*32 + g*8);
      wb[i][ks] = ld8(wp  + (i*16 + c)*64 + ks*32 + g*8);
    }
  u16* op = ao + (long)b*NTOK*DM + (long)h*64;

  for (int tt = 0; tt < 4; ++tt) {
    const int tok0 = qd*1024 + tt*256 + w*64;
    const u16* qp = q + ((long)bh*NTOK + tok0)*DH;
    s16x8 aq[4][2];
    #pragma unroll
    for (int i = 0; i < 4; ++i)
      #pragma unroll
      for (int ks = 0; ks < 2; ++ks)
        aq[i][ks] = ld8(qp + (long)(i*16 + c)*DH + ks*32 + g*8);
    f32x4 sacc[4][4] = {};
    #pragma unroll
    for (int ks = 0; ks < 2; ++ks)
      #pragma unroll
      for (int mi = 0; mi < 4; ++mi)
        #pragma unroll
        for (int ni = 0; ni < 4; ++ni)
          sacc[mi][ni] = __builtin_amdgcn_mfma_f32_16x16x32_bf16(aq[mi][ks], kb[ni][ks], sacc[mi][ni], 0, 0, 0);

    float rs[4][4];
    #pragma unroll
    for (int mi = 0; mi < 4; ++mi)
      #pragma unroll
      for (int r = 0; r < 4; ++r) {
        const int row = mi*16 + g*4 + r;
        char* base = pbase + row*P1ST;
        float ssum = 0.f;
        #pragma unroll
        for (int ni = 0; ni < 4; ++ni) {
          const float p = __expf(sacc[mi][ni][r]);
          ssum += p;
          *(u16*)(base + (ni*16 + c)*2) = f2b(p);
        }
        ssum += __shfl_xor(ssum, 1); ssum += __shfl_xor(ssum, 2);
        ssum += __shfl_xor(ssum, 4); ssum += __shfl_xor(ssum, 8);
        rs[mi][r] = ssum;
      }
    asm volatile("s_waitcnt lgkmcnt(0)" ::: "memory");   // wave-local store->read ordering
    s16x8 pa[4][2];
    #pragma unroll
    for (int mi = 0; mi < 4; ++mi)
      #pragma unroll
      for (int ks = 0; ks < 2; ++ks)
        pa[mi][ks] = *(const s16x8*)(pbase + (mi*16 + c)*P1ST + ks*64 + g*16);
    f32x4 oacc[4][4] = {};
    #pragma unroll
    for (int ks = 0; ks < 2; ++ks)
      #pragma unroll
      for (int mi = 0; mi < 4; ++mi)
        #pragma unroll
        for (int ni = 0; ni < 4; ++ni)
          oacc[mi][ni] = __builtin_amdgcn_mfma_f32_16x16x32_bf16(pa[mi][ks], wb[ni][ks], oacc[mi][ni], 0, 0, 0);

    #pragma unroll
    for (int mi = 0; mi < 4; ++mi)
      #pragma unroll
      for (int r = 0; r < 4; ++r) {
        const int tok = tok0 + mi*16 + g*4 + r;
        const float inv = 1.0f / rs[mi][r];
        #pragma unroll
        for (int ni = 0; ni < 4; ++ni)
          op[(long)tok*DM + ni*16 + c] = f2b(oacc[mi][ni][r] * inv);
      }
    asm volatile("s_waitcnt lgkmcnt(0)" ::: "memory");   // P reads done before next iter overwrites
  }
}

extern "C" void kernel_launch(void* const* d_in, const int* in_sizes, int n_in,
                              void* d_out, int out_size, void* d_ws, size_t ws_size,
                              hipStream_t stream) {
  const float* hs   = (const float*)d_in[0];
  const float* Wqkv = (const float*)d_in[1];
  const float* bqkv = (const float*)d_in[2];
  const float* Wout = (const float*)d_in[3];
  const float* bout = (const float*)d_in[4];
  float* out = (float*)d_out;
  char* w = (char*)d_ws;

  u16*  Xb    = (u16*)(w);                 // 32MB; dead after gemm0
  float* zp   = (float*)(w);               // aliases Xb (written by k_pa after gemm0), 8MB
  float* sp   = (float*)(w + 8388608L);
  u16*  WqkvT = (u16*)(w + 33554432L);
  u16*  WoutT = (u16*)(w + 39845888L);
  u16*  q     = (u16*)(w + 41943040L);
  float* psum = (float*)(w + 41943040L);   // aliases q: consumed by k_lreduce BEFORE gemm0 writes q
  u16*  k     = (u16*)(w + 75497472L);
  float* Xl   = (float*)(w + 109051904L);
  u16*  vt    = (u16*)(w + 142606336L);    // written directly by gemm0's V epilogue
  float* qlf  = (float*)(w + 176160768L);
  float* klf  = (float*)(w + 177209344L);
  u16*  qlb   = (u16*)(w + 178257920L);
  u16*  klb   = (u16*)(w + 178782208L);
  float* a2i  = (float*)(w + 179306496L);
  u16*  w2t   = (u16*)(w + 181403648L);
  u16*  ao    = (u16*)(w + 181927936L);

  k_pre<<<2048, 256, 0, stream>>>(hs, Xb, Xl, Wqkv, WqkvT, Wout, WoutT);
  k_lproj2<<<dim3(8,8,8), 256, 0, stream>>>(Xl, Wqkv, psum);
  k_lreduce<<<2048, 256, 0, stream>>>(psum, bqkv, qlf, klf, qlb, klb);
  k_gemm256<0><<<dim3(64,12), 512, 0, stream>>>(Xb, WqkvT, bqkv, 3072, nullptr, q, k, vt);
  k_pa<<<576, 1024, 0, stream>>>(qlf, klf, a2i, qlb, k, vt, zp, sp);
  k_w2<<<64, 1024, 0, stream>>>(a2i, zp, sp, w2t);
  k_attn1<<<256, 256, 0, stream>>>(q, klb, w2t, ao);
  k_gemm256<1><<<dim3(64,4), 512, 0, stream>>>(ao, WoutT, bout, 1024, out, nullptr, nullptr, nullptr);
}

// Round 14
// 328.539 us; speedup vs baseline: 1.0723x; 1.0723x over previous
//
#include <hip/hip_runtime.h>
#include <cstdint>

typedef unsigned short u16;
typedef __attribute__((ext_vector_type(8))) short s16x8;
typedef __attribute__((ext_vector_type(4))) float f32x4;

#define NTOK 4096
#define DH   64
#define DM   1024
#define NH   16

static __device__ __forceinline__ float b2f(u16 u){ return __uint_as_float(((unsigned)u)<<16); }
static __device__ __forceinline__ u16 f2b(float f){
  unsigned u = __float_as_uint(f);
  return (u16)((u + 0x7FFFu + ((u>>16)&1u)) >> 16);   // RNE
}

static __device__ __forceinline__ void gload_lds16(const void* g, void* l) {
  __builtin_amdgcn_global_load_lds(
      (const __attribute__((address_space(1))) unsigned*)(uintptr_t)g,
      (__attribute__((address_space(3))) unsigned*)(uintptr_t)l, 16, 0, 0);
}

static __device__ __forceinline__ s16x8 ld8(const u16* p){ return *(const s16x8*)(const void*)p; }

// ---------------- merged pre-pass: cvt_xl (1024 blks) | cvt_t Wqkv (768) | cvt_t Wout (256) ----------------
__global__ __launch_bounds__(256) void k_pre(const float* __restrict__ hs, u16* __restrict__ Xb,
                                             float* __restrict__ Xl,
                                             const float* __restrict__ Wqkv, u16* __restrict__ WqkvT,
                                             const float* __restrict__ Wout, u16* __restrict__ WoutT) {
  __shared__ float tile[64][65];
  const int bid = blockIdx.x, t = threadIdx.x;
  if (bid < 1024) {
    const int grp = bid >> 2;
    const int d = (bid & 3)*256 + t;
    const float* p = hs + (long)grp*64*DM + d;
    u16* xo = Xb + (long)grp*64*DM + d;
    float s = 0.f;
    #pragma unroll 8
    for (int i = 0; i < 64; ++i) {
      const float v = p[(long)i*DM];
      s += v;
      xo[(long)i*DM] = f2b(v);
    }
    Xl[(long)grp*DM + d] = s * (1.0f/64.0f);
    return;
  }
  const float* in; u16* out; int R, C, tc, tr;
  if (bid < 1792) { const int x = bid - 1024; in = Wqkv; out = WqkvT; R = 1024; C = 3072; tc = x % 48; tr = x / 48; }
  else            { const int x = bid - 1792; in = Wout; out = WoutT; R = 1024; C = 1024; tc = x & 15;  tr = x >> 4; }
  const int cx = t & 63, ry = t >> 6;
  #pragma unroll
  for (int p = 0; p < 16; ++p) {
    const int row = p*4 + ry;
    tile[row][cx] = in[(long)(tr*64 + row)*C + tc*64 + cx];
  }
  __syncthreads();
  #pragma unroll
  for (int p = 0; p < 16; ++p) {
    const int orow = p*4 + ry;
    out[(long)(tc*64 + orow)*R + tr*64 + cx] = f2b(tile[cx][orow]);
  }
}

// ---------------- fp32 projection, K-split: psum[z][row][col] partials ----------------
__global__ __launch_bounds__(256) void k_lproj2(const float* __restrict__ Xl, const float* __restrict__ Wqkv,
                                                float* __restrict__ psum) {
  __shared__ __align__(16) float Xs[32][68];
  const int t = threadIdx.x;
  const int wcol = blockIdx.x*256 + t;    // 0..2047
  const int r0 = blockIdx.y*32;
  const int kbase = blockIdx.z*128;
  float acc[32];
  #pragma unroll
  for (int r = 0; r < 32; ++r) acc[r] = 0.f;
  for (int k0 = kbase; k0 < kbase + 128; k0 += 64) {
    __syncthreads();
    for (int idx = t; idx < 2048; idx += 256)
      Xs[idx>>6][idx&63] = Xl[(long)(r0 + (idx>>6))*DM + k0 + (idx&63)];
    __syncthreads();
    for (int kk = 0; kk < 64; kk += 4) {
      f32x4 wv;
      #pragma unroll
      for (int j = 0; j < 4; ++j) wv[j] = Wqkv[(long)(k0+kk+j)*3072 + wcol];
      #pragma unroll
      for (int r = 0; r < 32; ++r) {
        const f32x4 xv = *(const f32x4*)&Xs[r][kk];
        acc[r] += xv[0]*wv[0] + xv[1]*wv[1] + xv[2]*wv[2] + xv[3]*wv[3];
      }
    }
  }
  float* po = psum + ((long)blockIdx.z*256 + r0)*2048 + wcol;
  #pragma unroll
  for (int r = 0; r < 32; ++r) po[(long)r*2048] = acc[r];
}

// ---------------- reduce K-slices + bias + scale -> qlf/klf/qlb/klb ----------------
__global__ __launch_bounds__(256) void k_lreduce(const float* __restrict__ psum, const float* __restrict__ bqkv,
                                                 float* __restrict__ qlf, float* __restrict__ klf,
                                                 u16* __restrict__ qlb, u16* __restrict__ klb) {
  const long idx = (long)blockIdx.x*256 + threadIdx.x;
  const int row = (int)(idx >> 11), col = (int)(idx & 2047);
  float s = 0.f;
  #pragma unroll
  for (int z = 0; z < 8; ++z) s += psum[((long)z*256 + row)*2048 + col];
  const int isq = (col < 1024) ? 1 : 0;
  float val = s + bqkv[col];
  if (isq) val *= 0.125f;
  const int b = row >> 6, lm = row & 63;
  const int c2 = col & 1023, h = c2 >> 6, dh = c2 & 63;
  const long o = (((long)b*NH + h)*64 + lm)*64 + dh;
  if (isq) { qlf[o] = val; qlb[o] = f2b(val); }
  else     { klf[o] = val; klb[o] = f2b(val); }
}

// ---------------- GEMM 256x256, BK=64, 8 waves, 2x64KB dbuf, 8-phase schedule (r12, kept) ----------------
template<int EPI>
__global__ __launch_bounds__(512, 2) void k_gemm256(
    const u16* __restrict__ A, const u16* __restrict__ Bt, const float* __restrict__ bias,
    int N, float* __restrict__ outF, u16* __restrict__ outQ, u16* __restrict__ outK, u16* __restrict__ outV)
{
  __shared__ __align__(16) u16 lds[2*32768];
  const int t = threadIdx.x;
  const int lane = t & 63;
  const int wid = t >> 6;
  const int c = lane & 15, g = lane >> 4;
  const int wm = wid >> 2, wn = wid & 3;
  const int fid = blockIdx.y*64 + blockIdx.x;
  const int nbx = ((fid & 7) << 3) | ((fid >> 3) & 7);
  const int nby = fid >> 6;
  const long arow0 = (long)nbx * 256;
  const long brow0 = (long)nby * 256;
  char* ldsb = (char*)lds;

  const int srow3 = t >> 3;
  const int sch = ((t & 7) ^ (srow3 & 7)) * 8;
  const u16* sA = A  + (arow0 + srow3)*1024 + sch;
  const u16* sB = Bt + (brow0 + srow3)*1024 + sch;
  const int dbase = t*16;

#define STG(gp, R0, Toff, kbe, nb) { \
    char* d0 = ldsb + (nb)*65536 + (Toff) + (R0)*128 + dbase; \
    gload_lds16((gp) + (long)(R0)*1024 + (kbe), d0); \
    gload_lds16((gp) + (long)((R0)+64)*1024 + (kbe), d0 + 8192); }

  const int cp0 = ((g     ) ^ (c & 7)) * 16;
  const int cp1 = ((4 | g ) ^ (c & 7)) * 16;
  int rowA[4], rowB[4];
  #pragma unroll
  for (int mi = 0; mi < 4; ++mi) {
    rowA[mi] = (wm*64 + mi*16 + c)*128;
    rowB[mi] = 32768 + (wn*64 + mi*16 + c)*128;
  }

  f32x4 acc0[4][4] = {};
  f32x4 acc1[4][4] = {};

  STG(sB, 0, 32768, 0, 0)
  STG(sB, 128, 32768, 0, 0)
  STG(sA, 0, 0, 0, 0)
  STG(sA, 128, 0, 0, 0)
  asm volatile("s_waitcnt vmcnt(2)" ::: "memory");
  __builtin_amdgcn_s_barrier();

  for (int it = 0; it < 16; ++it) {
    char* buf = ldsb + (it&1)*65536;
    const int nb = (it+1)&1;
    const int kb1 = (it+1)*64;
    const bool last = (it == 15);
    s16x8 fa[4], fb[4], ga[4];
    // ---- P0 ----
    #pragma unroll
    for (int mi = 0; mi < 4; ++mi) fa[mi] = *(const s16x8*)(buf + rowA[mi] + cp0);
    #pragma unroll
    for (int ni = 0; ni < 4; ++ni) fb[ni] = *(const s16x8*)(buf + rowB[ni] + cp0);
    if (!last) STG(sB, 0, 32768, kb1, nb)
    __builtin_amdgcn_s_barrier();
    asm volatile("s_waitcnt lgkmcnt(0)" ::: "memory");
    __builtin_amdgcn_sched_barrier(0);
    __builtin_amdgcn_s_setprio(1);
    #pragma unroll
    for (int mi = 0; mi < 4; ++mi)
      #pragma unroll
      for (int ni = 0; ni < 4; ++ni)
        acc0[mi][ni] = __builtin_amdgcn_mfma_f32_16x16x32_bf16(fa[mi], fb[ni], acc0[mi][ni], 0, 0, 0);
    __builtin_amdgcn_s_setprio(0);
    if (last) { asm volatile("s_waitcnt vmcnt(0)" ::: "memory"); }
    else      { asm volatile("s_waitcnt vmcnt(2)" ::: "memory"); }
    __builtin_amdgcn_s_barrier();
    // ---- P1 ----
    #pragma unroll
    for (int mi = 0; mi < 4; ++mi) ga[mi] = *(const s16x8*)(buf + rowA[mi] + 16384 + cp0);
    if (!last) STG(sB, 128, 32768, kb1, nb)
    __builtin_amdgcn_s_barrier();
    asm volatile("s_waitcnt lgkmcnt(0)" ::: "memory");
    __builtin_amdgcn_sched_barrier(0);
    __builtin_amdgcn_s_setprio(1);
    #pragma unroll
    for (int mi = 0; mi < 4; ++mi)
      #pragma unroll
      for (int ni = 0; ni < 4; ++ni)
        acc1[mi][ni] = __builtin_amdgcn_mfma_f32_16x16x32_bf16(ga[mi], fb[ni], acc1[mi][ni], 0, 0, 0);
    __builtin_amdgcn_s_setprio(0);
    __builtin_amdgcn_s_barrier();
    // ---- P2 ----
    #pragma unroll
    for (int mi = 0; mi < 4; ++mi) fa[mi] = *(const s16x8*)(buf + rowA[mi] + cp1);
    #pragma unroll
    for (int ni = 0; ni < 4; ++ni) fb[ni] = *(const s16x8*)(buf + rowB[ni] + cp1);
    if (!last) STG(sA, 0, 0, kb1, nb)
    __builtin_amdgcn_s_barrier();
    asm volatile("s_waitcnt lgkmcnt(0)" ::: "memory");
    __builtin_amdgcn_sched_barrier(0);
    __builtin_amdgcn_s_setprio(1);
    #pragma unroll
    for (int mi = 0; mi < 4; ++mi)
      #pragma unroll
      for (int ni = 0; ni < 4; ++ni)
        acc0[mi][ni] = __builtin_amdgcn_mfma_f32_16x16x32_bf16(fa[mi], fb[ni], acc0[mi][ni], 0, 0, 0);
    __builtin_amdgcn_s_setprio(0);
    __builtin_amdgcn_s_barrier();
    // ---- P3 ----
    #pragma unroll
    for (int mi = 0; mi < 4; ++mi) ga[mi] = *(const s16x8*)(buf + rowA[mi] + 16384 + cp1);
    if (!last) STG(sA, 128, 0, kb1, nb)
    __builtin_amdgcn_s_barrier();
    asm volatile("s_waitcnt lgkmcnt(0)" ::: "memory");
    __builtin_amdgcn_sched_barrier(0);
    __builtin_amdgcn_s_setprio(1);
    #pragma unroll
    for (int mi = 0; mi < 4; ++mi)
      #pragma unroll
      for (int ni = 0; ni < 4; ++ni)
        acc1[mi][ni] = __builtin_amdgcn_mfma_f32_16x16x32_bf16(ga[mi], fb[ni], acc1[mi][ni], 0, 0, 0);
    __builtin_amdgcn_s_setprio(0);
    if (!last) { asm volatile("s_waitcnt vmcnt(2)" ::: "memory"); }
    __builtin_amdgcn_s_barrier();
  }
#undef STG

  if (EPI == 0) {
    const int tensor = (int)(brow0 >> 10);
    if (tensor == 2) {
      __syncthreads();
      u16* wlds = lds + wid*4224;
      const int hbase = (int)((brow0 + wn*64) & 1023);
      const int head = hbase >> 6;
      #pragma unroll
      for (int ph = 0; ph < 2; ++ph) {
        const long grow0 = arow0 + ph*128 + wm*64;
        const int b = (int)(grow0 >> 12), tok0r = (int)(grow0 & 4095);
        #pragma unroll
        for (int mi = 0; mi < 4; ++mi)
          #pragma unroll
          for (int ni = 0; ni < 4; ++ni) {
            const float bv = bias[brow0 + wn*64 + ni*16 + c];
            const f32x4 a = ph ? acc1[mi][ni] : acc0[mi][ni];
            #pragma unroll
            for (int r = 0; r < 4; ++r)
              wlds[(mi*16 + g*4 + r)*66 + ni*16 + c] = f2b(a[r] + bv);
          }
        asm volatile("s_waitcnt lgkmcnt(0)" ::: "memory");
        u16* vbase = outV + (((long)b*NH + head)*DH)*NTOK + tok0r;
        #pragma unroll
        for (int j = 0; j < 8; ++j) {
          const int d = j*8 + (lane >> 3);
          const int tk = (lane & 7)*8;
          s16x8 vv;
          #pragma unroll
          for (int s2 = 0; s2 < 8; ++s2) vv[s2] = (short)wlds[(tk + s2)*66 + d];
          *(s16x8*)(vbase + (long)d*NTOK + tk) = vv;
        }
        asm volatile("s_waitcnt lgkmcnt(0)" ::: "memory");
      }
    } else {
      u16* dst = (tensor == 0) ? outQ : outK;
      const float mul = (tensor == 0) ? 0.125f : 1.0f;
      #pragma unroll
      for (int ph = 0; ph < 2; ++ph)
        #pragma unroll
        for (int mi = 0; mi < 4; ++mi) {
          const int rowb = ph*128 + wm*64 + mi*16 + g*4;
          #pragma unroll
          for (int ni = 0; ni < 4; ++ni) {
            const long gcol = brow0 + wn*64 + ni*16 + c;
            const int c2 = (int)(gcol & 1023);
            const int head = c2 >> 6, dh = c2 & 63;
            const float bv = bias[gcol];
            const f32x4 a = ph ? acc1[mi][ni] : acc0[mi][ni];
            #pragma unroll
            for (int r = 0; r < 4; ++r) {
              const long grow = arow0 + rowb + r;
              const int b = (int)(grow >> 12), tok = (int)(grow & 4095);
              dst[(((long)b*NH + head)*NTOK + tok)*DH + dh] = f2b((a[r] + bv)*mul);
            }
          }
        }
    }
  } else {
    #pragma unroll
    for (int ph = 0; ph < 2; ++ph)
      #pragma unroll
      for (int mi = 0; mi < 4; ++mi) {
        const int rowb = ph*128 + wm*64 + mi*16 + g*4;
        #pragma unroll
        for (int ni = 0; ni < 4; ++ni) {
          const long gcol = brow0 + wn*64 + ni*16 + c;
          const float bv = bias[gcol];
          const f32x4 a = ph ? acc1[mi][ni] : acc0[mi][ni];
          #pragma unroll
          for (int r = 0; r < 4; ++r) {
            const long grow = arow0 + rowb + r;
            outF[grow*N + gcol] = a[r] + bv;
          }
        }
      }
  }
}

// ---------------- fp32 LDS 64x64 matmul helpers ----------------
#define PST 68
static __device__ __forceinline__ void mm_nn8(const float* A, const float* B, float* C, int t) {
  const int lane = t & 63, j0 = (t >> 6) << 3;
  float acc[8];
  #pragma unroll
  for (int j = 0; j < 8; ++j) acc[j] = 0.f;
  for (int k = 0; k < 64; k += 4) {
    const f32x4 a4 = *(const f32x4*)&A[lane*PST + k];
    #pragma unroll
    for (int dk = 0; dk < 4; ++dk) {
      const float a = a4[dk];
      const float* br = &B[(k + dk)*PST + j0];
      const f32x4 b0 = *(const f32x4*)(br);
      const f32x4 b1 = *(const f32x4*)(br + 4);
      #pragma unroll
      for (int qq = 0; qq < 4; ++qq) { acc[qq] += a*b0[qq]; acc[4+qq] += a*b1[qq]; }
    }
  }
  #pragma unroll
  for (int j = 0; j < 8; ++j) C[lane*PST + j0 + j] = acc[j];
}
static __device__ __forceinline__ void mm_nt8(const float* A, const float* B, float* C, int t) {
  const int lane = t & 63, j0 = (t >> 6) << 3;
  float acc[8];
  #pragma unroll
  for (int j = 0; j < 8; ++j) acc[j] = 0.f;
  for (int k = 0; k < 64; k += 4) {
    const f32x4 a4 = *(const f32x4*)&A[lane*PST + k];
    #pragma unroll
    for (int jj = 0; jj < 8; ++jj) {
      const f32x4 b4 = *(const f32x4*)&B[(j0 + jj)*PST + k];
      acc[jj] += a4[0]*b4[0] + a4[1]*b4[1] + a4[2]*b4[2] + a4[3]*b4[3];
    }
  }
  #pragma unroll
  for (int j = 0; j < 8; ++j) C[lane*PST + j0 + j] = acc[j];
}
static __device__ __forceinline__ void mm_nn4(const float* A, const float* B, float* C, int t) {
  const int lane = t & 63, j0 = (t >> 6) << 2;
  float acc[4] = {0.f, 0.f, 0.f, 0.f};
  for (int k = 0; k < 64; k += 4) {
    const f32x4 a4 = *(const f32x4*)&A[lane*PST + k];
    #pragma unroll
    for (int dk = 0; dk < 4; ++dk) {
      const f32x4 b0 = *(const f32x4*)&B[(k + dk)*PST + j0];
      #pragma unroll
      for (int q = 0; q < 4; ++q) acc[q] += a4[dk]*b0[q];
    }
  }
  #pragma unroll
  for (int j = 0; j < 4; ++j) C[lane*PST + j0 + j] = acc[j];
}

// ---------------- merged: pinv (blocks 0..63) | attn3v partials (blocks 64..575), 512 thr ----------------
__global__ __launch_bounds__(512) void k_pa(const float* __restrict__ qlf, const float* __restrict__ klf,
                                            float* __restrict__ a2inv,
                                            const u16* __restrict__ qlb, const u16* __restrict__ kk,
                                            const u16* __restrict__ vt,
                                            float* __restrict__ zp, float* __restrict__ sp) {
  __shared__ __align__(16) char smem[87040];
  const int t = threadIdx.x;
  if (blockIdx.x < 64) {
    float* Xb = (float*)smem;
    float* Vb = Xb + 64*PST;
    float* T1 = Vb + 64*PST;
    float* T2 = T1 + 64*PST;
    float* T3 = T2 + 64*PST;
    const int bh = blockIdx.x;
    const float* ql = qlf + (long)bh*4096;
    const float* kl = klf + (long)bh*4096;
    for (int i = t; i < 4096; i += 512) { T1[(i>>6)*PST + (i&63)] = ql[i]; T2[(i>>6)*PST + (i&63)] = kl[i]; }
    __syncthreads();
    mm_nt8(T1, T2, Xb, t);
    __syncthreads();
    if (t < 64) {
      float mx = -1e30f;
      for (int j = 0; j < 64; ++j) mx = fmaxf(mx, Xb[t*PST + j]);
      float s = 0.f;
      for (int j = 0; j < 64; ++j) { const float e = expf(Xb[t*PST + j] - mx); Xb[t*PST + j] = e; s += e; }
      const float inv = 1.0f/s;
      for (int j = 0; j < 64; ++j) Xb[t*PST + j] *= inv;
    }
    __syncthreads();
    for (int i = t; i < 4096; i += 512) { const int r = i>>6, cc = i&63; Vb[r*PST+cc] = Xb[r*PST+cc]; }
    __syncthreads();
    for (int it = 0; it < 6; ++it) {
      mm_nn8(Xb, Vb, T1, t);  __syncthreads();
      for (int i = t; i < 4096; i += 512) { const int r=i>>6, cc=i&63; T2[r*PST+cc] = (r==cc?7.0f:0.0f) - T1[r*PST+cc]; }
      __syncthreads();
      mm_nn8(T1, T2, T3, t);  __syncthreads();
      for (int i = t; i < 4096; i += 512) { const int r=i>>6, cc=i&63; T2[r*PST+cc] = (r==cc?15.0f:0.0f) - T3[r*PST+cc]; }
      __syncthreads();
      mm_nn8(T1, T2, T3, t);  __syncthreads();
      for (int i = t; i < 4096; i += 512) { const int r=i>>6, cc=i&63; T2[r*PST+cc] = (r==cc?13.0f:0.0f) - T3[r*PST+cc]; }
      __syncthreads();
      mm_nn8(Vb, T2, T3, t);  __syncthreads();
      for (int i = t; i < 4096; i += 512) { const int r=i>>6, cc=i&63; Vb[r*PST+cc] = 0.25f*T3[r*PST+cc]; }
      __syncthreads();
    }
    for (int i = t; i < 4096; i += 512) a2inv[(long)bh*4096 + i] = Vb[(i>>6)*PST + (i&63)];
    return;
  }
  float* Zlp = (float*)smem;               // [4][64][64]
  float* Slp = (float*)(smem + 65536);     // [4][64]
  char*  Plb = smem + 66560;               // [4][64][80B]
  const int abid = blockIdx.x - 64;
  const int bh = abid >> 3, qt = abid & 7;
  if (t < 256) {
    const int w = t >> 6, lane = t & 63;
    const int c = lane & 15, g = lane >> 4;
    s16x8 aq[4][2];
    const u16* qlp = qlb + (long)bh*4096;
    #pragma unroll
    for (int mi = 0; mi < 4; ++mi)
      #pragma unroll
      for (int ks = 0; ks < 2; ++ks)
        aq[mi][ks] = ld8(qlp + (mi*16 + c)*64 + ks*32 + g*8);

    f32x4 zacc[4][4] = {};
    float sl[4][4] = {};
    const u16* kp = kk + (long)bh*NTOK*DH;
    const u16* vp = vt + (long)bh*DH*NTOK;
    char* pbase = Plb + w*5120;
    const int tok00 = qt*512 + w*128;

    for (int it = 0; it < 4; ++it) {
      const int t0 = tok00 + it*32;
      f32x4 sacc[4][2] = {};
      s16x8 kb[2][2];
      #pragma unroll
      for (int cg = 0; cg < 2; ++cg)
        #pragma unroll
        for (int ks = 0; ks < 2; ++ks)
          kb[cg][ks] = ld8(kp + (long)(t0 + cg*16 + c)*64 + ks*32 + g*8);
      #pragma unroll
      for (int cg = 0; cg < 2; ++cg)
        #pragma unroll
        for (int ks = 0; ks < 2; ++ks)
          #pragma unroll
          for (int mi = 0; mi < 4; ++mi)
            sacc[mi][cg] = __builtin_amdgcn_mfma_f32_16x16x32_bf16(aq[mi][ks], kb[cg][ks], sacc[mi][cg], 0, 0, 0);
      #pragma unroll
      for (int mi = 0; mi < 4; ++mi)
        #pragma unroll
        for (int r = 0; r < 4; ++r) {
          const int row = mi*16 + g*4 + r;
          const float p0 = __expf(sacc[mi][0][r]);
          const float p1 = __expf(sacc[mi][1][r]);
          sl[mi][r] += p0 + p1;
          char* base = pbase + row*80;
          *(u16*)(base + c*2)      = f2b(p0);
          *(u16*)(base + 32 + c*2) = f2b(p1);
        }
      s16x8 pa[4];
      #pragma unroll
      for (int mi = 0; mi < 4; ++mi) pa[mi] = *(const s16x8*)(pbase + (mi*16 + c)*80 + g*16);
      #pragma unroll
      for (int ni = 0; ni < 4; ++ni) {
        const s16x8 vb = ld8(vp + (long)(ni*16 + c)*NTOK + t0 + g*8);
        #pragma unroll
        for (int mi = 0; mi < 4; ++mi)
          zacc[mi][ni] = __builtin_amdgcn_mfma_f32_16x16x32_bf16(pa[mi], vb, zacc[mi][ni], 0, 0, 0);
      }
    }
    #pragma unroll
    for (int mi = 0; mi < 4; ++mi)
      #pragma unroll
      for (int r = 0; r < 4; ++r) {
        float s = sl[mi][r];
        s += __shfl_xor(s, 1); s += __shfl_xor(s, 2); s += __shfl_xor(s, 4); s += __shfl_xor(s, 8);
        sl[mi][r] = s;
      }
    #pragma unroll
    for (int mi = 0; mi < 4; ++mi)
      #pragma unroll
      for (int ni = 0; ni < 4; ++ni)
        #pragma unroll
        for (int r = 0; r < 4; ++r)
          Zlp[w*4096 + (mi*16 + g*4 + r)*64 + ni*16 + c] = zacc[mi][ni][r];
    if (c == 0)
      #pragma unroll
      for (int mi = 0; mi < 4; ++mi)
        #pragma unroll
        for (int r = 0; r < 4; ++r)
          Slp[w*64 + mi*16 + g*4 + r] = sl[mi][r];
  }
  __syncthreads();
  float* zpp = zp + (long)abid*4096;
  for (int i = t; i < 4096; i += 512)
    zpp[i] = Zlp[i] + Zlp[4096 + i] + Zlp[8192 + i] + Zlp[12288 + i];
  if (t < 64) sp[(long)abid*64 + t] = Slp[t] + Slp[64 + t] + Slp[128 + t] + Slp[192 + t];
}

// ---------------- fused: z-reduce + W2^T = (attn2inv @ z)^T  (bf16 [dh][lm], 1024 thr) ----------------
__global__ __launch_bounds__(1024) void k_w2(const float* __restrict__ a2inv,
                                             const float* __restrict__ zp, const float* __restrict__ sp,
                                             u16* __restrict__ w2t) {
  __shared__ __align__(16) float Ai[64*PST];
  __shared__ __align__(16) float Zi[64*PST];
  __shared__ __align__(16) float Ci[64*PST];
  __shared__ float Ss[64];
  const int bh = blockIdx.x, t = threadIdx.x;
  if (t < 64) {
    float ss = 0.f;
    #pragma unroll
    for (int qt = 0; qt < 8; ++qt) ss += sp[(long)(bh*8 + qt)*64 + t];
    Ss[t] = 1.0f / ss;
  }
  for (int i = t; i < 4096; i += 1024)
    Ai[(i>>6)*PST + (i&63)] = a2inv[(long)bh*4096 + i];
  __syncthreads();
  for (int i = t; i < 4096; i += 1024) {
    float zs = 0.f;
    #pragma unroll
    for (int qt = 0; qt < 8; ++qt) zs += zp[((long)(bh*8 + qt))*4096 + i];
    Zi[(i>>6)*PST + (i&63)] = zs * Ss[i>>6];
  }
  __syncthreads();
  mm_nn4(Ai, Zi, Ci, t);
  __syncthreads();
  for (int i = t; i < 4096; i += 1024) { const int r = i>>6, cc = i&63; w2t[(long)bh*4096 + cc*64 + r] = f2b(Ci[r*PST + cc]); }
}

// ---------------- out_h = softmax(q @ k_l^T) @ W2: 512 blocks, 2 token-tiles/block ----------------
#define P1ST 144
__global__ __launch_bounds__(256) void k_attn1(const u16* __restrict__ q, const u16* __restrict__ klb,
                                               const u16* __restrict__ w2t, u16* __restrict__ ao) {
  __shared__ __align__(16) u16 Pl[4][64][72];
  const int bx = blockIdx.x, bh = bx >> 3, qd = bx & 7;
  const int b = bh >> 4, h = bh & 15;
  const int t = threadIdx.x, w = t >> 6, lane = t & 63;
  const int c = lane & 15, g = lane >> 4;
  const u16* klp = klb + (long)bh*4096;
  const u16* wp  = w2t + (long)bh*4096;
  char* pbase = (char*)&Pl[w][0][0];

  s16x8 kb[4][2], wb[4][2];
  #pragma unroll
  for (int i = 0; i < 4; ++i)
    #pragma unroll
    for (int ks = 0; ks < 2; ++ks) {
      kb[i][ks] = ld8(klp + (i*16 + c)*64 + ks*32 + g*8);
      wb[i][ks] = ld8(wp  + (i*16 + c)*64 + ks*32 + g*8);
    }
  u16* op = ao + (long)b*NTOK*DM + (long)h*64;

  for (int tt = 0; tt < 2; ++tt) {
    const int tok0 = qd*512 + tt*256 + w*64;
    const u16* qp = q + ((long)bh*NTOK + tok0)*DH;
    s16x8 aq[4][2];
    #pragma unroll
    for (int i = 0; i < 4; ++i)
      #pragma unroll
      for (int ks = 0; ks < 2; ++ks)
        aq[i][ks] = ld8(qp + (long)(i*16 + c)*DH + ks*32 + g*8);
    f32x4 sacc[4][4] = {};
    #pragma unroll
    for (int ks = 0; ks < 2; ++ks)
      #pragma unroll
      for (int mi = 0; mi < 4; ++mi)
        #pragma unroll
        for (int ni = 0; ni < 4; ++ni)
          sacc[mi][ni] = __builtin_amdgcn_mfma_f32_16x16x32_bf16(aq[mi][ks], kb[ni][ks], sacc[mi][ni], 0, 0, 0);

    float rs[4][4];
    #pragma unroll
    for (int mi = 0; mi < 4; ++mi)
      #pragma unroll
      for (int r = 0; r < 4; ++r) {
        const int row = mi*16 + g*4 + r;
        char* base = pbase + row*P1ST;
        float ssum = 0.f;
        #pragma unroll
        for (int ni = 0; ni < 4; ++ni) {
          const float p = __expf(sacc[mi][ni][r]);
          ssum += p;
          *(u16*)(base + (ni*16 + c)*2) = f2b(p);
        }
        ssum += __shfl_xor(ssum, 1); ssum += __shfl_xor(ssum, 2);
        ssum += __shfl_xor(ssum, 4); ssum += __shfl_xor(ssum, 8);
        rs[mi][r] = ssum;
      }
    asm volatile("s_waitcnt lgkmcnt(0)" ::: "memory");   // wave-local store->read ordering (P tile is per-wave)
    s16x8 pa[4][2];
    #pragma unroll
    for (int mi = 0; mi < 4; ++mi)
      #pragma unroll
      for (int ks = 0; ks < 2; ++ks)
        pa[mi][ks] = *(const s16x8*)(pbase + (mi*16 + c)*P1ST + ks*64 + g*16);
    f32x4 oacc[4][4] = {};
    #pragma unroll
    for (int ks = 0; ks < 2; ++ks)
      #pragma unroll
      for (int mi = 0; mi < 4; ++mi)
        #pragma unroll
        for (int ni = 0; ni < 4; ++ni)
          oacc[mi][ni] = __builtin_amdgcn_mfma_f32_16x16x32_bf16(pa[mi][ks], wb[ni][ks], oacc[mi][ni], 0, 0, 0);

    #pragma unroll
    for (int mi = 0; mi < 4; ++mi)
      #pragma unroll
      for (int r = 0; r < 4; ++r) {
        const int tok = tok0 + mi*16 + g*4 + r;
        const float inv = 1.0f / rs[mi][r];
        #pragma unroll
        for (int ni = 0; ni < 4; ++ni)
          op[(long)tok*DM + ni*16 + c] = f2b(oacc[mi][ni][r] * inv);
      }
    asm volatile("s_waitcnt lgkmcnt(0)" ::: "memory");   // P reads drained before next iter overwrites
  }
}

extern "C" void kernel_launch(void* const* d_in, const int* in_sizes, int n_in,
                              void* d_out, int out_size, void* d_ws, size_t ws_size,
                              hipStream_t stream) {
  const float* hs   = (const float*)d_in[0];
  const float* Wqkv = (const float*)d_in[1];
  const float* bqkv = (const float*)d_in[2];
  const float* Wout = (const float*)d_in[3];
  const float* bout = (const float*)d_in[4];
  float* out = (float*)d_out;
  char* w = (char*)d_ws;

  u16*  Xb    = (u16*)(w);                 // 32MB; dead after gemm0
  float* zp   = (float*)(w);               // aliases Xb (written by k_pa after gemm0), 8MB
  float* sp   = (float*)(w + 8388608L);
  u16*  WqkvT = (u16*)(w + 33554432L);
  u16*  WoutT = (u16*)(w + 39845888L);
  u16*  q     = (u16*)(w + 41943040L);
  float* psum = (float*)(w + 41943040L);   // aliases q: consumed by k_lreduce BEFORE gemm0 writes q
  u16*  k     = (u16*)(w + 75497472L);
  float* Xl   = (float*)(w + 109051904L);
  u16*  vt    = (u16*)(w + 142606336L);    // written directly by gemm0's V epilogue
  float* qlf  = (float*)(w + 176160768L);
  float* klf  = (float*)(w + 177209344L);
  u16*  qlb   = (u16*)(w + 178257920L);
  u16*  klb   = (u16*)(w + 178782208L);
  float* a2i  = (float*)(w + 179306496L);
  u16*  w2t   = (u16*)(w + 181403648L);
  u16*  ao    = (u16*)(w + 181927936L);

  k_pre<<<2048, 256, 0, stream>>>(hs, Xb, Xl, Wqkv, WqkvT, Wout, WoutT);
  k_lproj2<<<dim3(8,8,8), 256, 0, stream>>>(Xl, Wqkv, psum);
  k_lreduce<<<2048, 256, 0, stream>>>(psum, bqkv, qlf, klf, qlb, klb);
  k_gemm256<0><<<dim3(64,12), 512, 0, stream>>>(Xb, WqkvT, bqkv, 3072, nullptr, q, k, vt);
  k_pa<<<576, 512, 0, stream>>>(qlf, klf, a2i, qlb, k, vt, zp, sp);
  k_w2<<<64, 1024, 0, stream>>>(a2i, zp, sp, w2t);
  k_attn1<<<512, 256, 0, stream>>>(q, klb, w2t, ao);
  k_gemm256<1><<<dim3(64,4), 512, 0, stream>>>(ao, WoutT, bout, 1024, out, nullptr, nullptr, nullptr);
}

// Round 15
// 325.571 us; speedup vs baseline: 1.0821x; 1.0091x over previous
//
#include <hip/hip_runtime.h>
#include <cstdint>

typedef unsigned short u16;
typedef __attribute__((ext_vector_type(8))) short s16x8;
typedef __attribute__((ext_vector_type(4))) float f32x4;

#define NTOK 4096
#define DH   64
#define DM   1024
#define NH   16

static __device__ __forceinline__ float b2f(u16 u){ return __uint_as_float(((unsigned)u)<<16); }
static __device__ __forceinline__ u16 f2b(float f){
  unsigned u = __float_as_uint(f);
  return (u16)((u + 0x7FFFu + ((u>>16)&1u)) >> 16);   // RNE
}

static __device__ __forceinline__ void gload_lds16(const void* g, void* l) {
  __builtin_amdgcn_global_load_lds(
      (const __attribute__((address_space(1))) unsigned*)(uintptr_t)g,
      (__attribute__((address_space(3))) unsigned*)(uintptr_t)l, 16, 0, 0);
}

static __device__ __forceinline__ s16x8 ld8(const u16* p){ return *(const s16x8*)(const void*)p; }

// ---------------- merged pre-pass: cvt_xl (1024 blks) | cvt_t Wqkv (768) | cvt_t Wout (256) ----------------
__global__ __launch_bounds__(256) void k_pre(const float* __restrict__ hs, u16* __restrict__ Xb,
                                             float* __restrict__ Xl,
                                             const float* __restrict__ Wqkv, u16* __restrict__ WqkvT,
                                             const float* __restrict__ Wout, u16* __restrict__ WoutT) {
  __shared__ float tile[64][65];
  const int bid = blockIdx.x, t = threadIdx.x;
  if (bid < 1024) {
    const int grp = bid >> 2;
    const int d = (bid & 3)*256 + t;
    const float* p = hs + (long)grp*64*DM + d;
    u16* xo = Xb + (long)grp*64*DM + d;
    float s = 0.f;
    #pragma unroll 8
    for (int i = 0; i < 64; ++i) {
      const float v = p[(long)i*DM];
      s += v;
      xo[(long)i*DM] = f2b(v);
    }
    Xl[(long)grp*DM + d] = s * (1.0f/64.0f);
    return;
  }
  const float* in; u16* out; int R, C, tc, tr;
  if (bid < 1792) { const int x = bid - 1024; in = Wqkv; out = WqkvT; R = 1024; C = 3072; tc = x % 48; tr = x / 48; }
  else            { const int x = bid - 1792; in = Wout; out = WoutT; R = 1024; C = 1024; tc = x & 15;  tr = x >> 4; }
  const int cx = t & 63, ry = t >> 6;
  #pragma unroll
  for (int p = 0; p < 16; ++p) {
    const int row = p*4 + ry;
    tile[row][cx] = in[(long)(tr*64 + row)*C + tc*64 + cx];
  }
  __syncthreads();
  #pragma unroll
  for (int p = 0; p < 16; ++p) {
    const int orow = p*4 + ry;
    out[(long)(tc*64 + orow)*R + tr*64 + cx] = f2b(tile[cx][orow]);
  }
}

// ---------------- fp32 projection, K-split: psum[z][row][col] partials ----------------
__global__ __launch_bounds__(256) void k_lproj2(const float* __restrict__ Xl, const float* __restrict__ Wqkv,
                                                float* __restrict__ psum) {
  __shared__ __align__(16) float Xs[32][68];
  const int t = threadIdx.x;
  const int wcol = blockIdx.x*256 + t;    // 0..2047
  const int r0 = blockIdx.y*32;
  const int kbase = blockIdx.z*128;
  float acc[32];
  #pragma unroll
  for (int r = 0; r < 32; ++r) acc[r] = 0.f;
  for (int k0 = kbase; k0 < kbase + 128; k0 += 64) {
    __syncthreads();
    for (int idx = t; idx < 2048; idx += 256)
      Xs[idx>>6][idx&63] = Xl[(long)(r0 + (idx>>6))*DM + k0 + (idx&63)];
    __syncthreads();
    for (int kk = 0; kk < 64; kk += 4) {
      f32x4 wv;
      #pragma unroll
      for (int j = 0; j < 4; ++j) wv[j] = Wqkv[(long)(k0+kk+j)*3072 + wcol];
      #pragma unroll
      for (int r = 0; r < 32; ++r) {
        const f32x4 xv = *(const f32x4*)&Xs[r][kk];
        acc[r] += xv[0]*wv[0] + xv[1]*wv[1] + xv[2]*wv[2] + xv[3]*wv[3];
      }
    }
  }
  float* po = psum + ((long)blockIdx.z*256 + r0)*2048 + wcol;
  #pragma unroll
  for (int r = 0; r < 32; ++r) po[(long)r*2048] = acc[r];
}

// ---------------- reduce K-slices + bias + scale -> qlf/klf/qlb/klb ----------------
__global__ __launch_bounds__(256) void k_lreduce(const float* __restrict__ psum, const float* __restrict__ bqkv,
                                                 float* __restrict__ qlf, float* __restrict__ klf,
                                                 u16* __restrict__ qlb, u16* __restrict__ klb) {
  const long idx = (long)blockIdx.x*256 + threadIdx.x;
  const int row = (int)(idx >> 11), col = (int)(idx & 2047);
  float s = 0.f;
  #pragma unroll
  for (int z = 0; z < 8; ++z) s += psum[((long)z*256 + row)*2048 + col];
  const int isq = (col < 1024) ? 1 : 0;
  float val = s + bqkv[col];
  if (isq) val *= 0.125f;
  const int b = row >> 6, lm = row & 63;
  const int c2 = col & 1023, h = c2 >> 6, dh = c2 & 63;
  const long o = (((long)b*NH + h)*64 + lm)*64 + dh;
  if (isq) { qlf[o] = val; qlb[o] = f2b(val); }
  else     { klf[o] = val; klb[o] = f2b(val); }
}

// ---------------- GEMM 256x256, BK=64, 8 waves, 2x64KB dbuf, 8-phase schedule (r12, kept) ----------------
template<int EPI>
__global__ __launch_bounds__(512, 2) void k_gemm256(
    const u16* __restrict__ A, const u16* __restrict__ Bt, const float* __restrict__ bias,
    int N, float* __restrict__ outF, u16* __restrict__ outQ, u16* __restrict__ outK, u16* __restrict__ outV)
{
  __shared__ __align__(16) u16 lds[2*32768];
  const int t = threadIdx.x;
  const int lane = t & 63;
  const int wid = t >> 6;
  const int c = lane & 15, g = lane >> 4;
  const int wm = wid >> 2, wn = wid & 3;
  const int fid = blockIdx.y*64 + blockIdx.x;
  const int nbx = ((fid & 7) << 3) | ((fid >> 3) & 7);
  const int nby = fid >> 6;
  const long arow0 = (long)nbx * 256;
  const long brow0 = (long)nby * 256;
  char* ldsb = (char*)lds;

  const int srow3 = t >> 3;
  const int sch = ((t & 7) ^ (srow3 & 7)) * 8;
  const u16* sA = A  + (arow0 + srow3)*1024 + sch;
  const u16* sB = Bt + (brow0 + srow3)*1024 + sch;
  const int dbase = t*16;

#define STG(gp, R0, Toff, kbe, nb) { \
    char* d0 = ldsb + (nb)*65536 + (Toff) + (R0)*128 + dbase; \
    gload_lds16((gp) + (long)(R0)*1024 + (kbe), d0); \
    gload_lds16((gp) + (long)((R0)+64)*1024 + (kbe), d0 + 8192); }

  const int cp0 = ((g     ) ^ (c & 7)) * 16;
  const int cp1 = ((4 | g ) ^ (c & 7)) * 16;
  int rowA[4], rowB[4];
  #pragma unroll
  for (int mi = 0; mi < 4; ++mi) {
    rowA[mi] = (wm*64 + mi*16 + c)*128;
    rowB[mi] = 32768 + (wn*64 + mi*16 + c)*128;
  }

  f32x4 acc0[4][4] = {};
  f32x4 acc1[4][4] = {};

  STG(sB, 0, 32768, 0, 0)
  STG(sB, 128, 32768, 0, 0)
  STG(sA, 0, 0, 0, 0)
  STG(sA, 128, 0, 0, 0)
  asm volatile("s_waitcnt vmcnt(2)" ::: "memory");
  __builtin_amdgcn_s_barrier();

  for (int it = 0; it < 16; ++it) {
    char* buf = ldsb + (it&1)*65536;
    const int nb = (it+1)&1;
    const int kb1 = (it+1)*64;
    const bool last = (it == 15);
    s16x8 fa[4], fb[4], ga[4];
    // ---- P0 ----
    #pragma unroll
    for (int mi = 0; mi < 4; ++mi) fa[mi] = *(const s16x8*)(buf + rowA[mi] + cp0);
    #pragma unroll
    for (int ni = 0; ni < 4; ++ni) fb[ni] = *(const s16x8*)(buf + rowB[ni] + cp0);
    if (!last) STG(sB, 0, 32768, kb1, nb)
    __builtin_amdgcn_s_barrier();
    asm volatile("s_waitcnt lgkmcnt(0)" ::: "memory");
    __builtin_amdgcn_sched_barrier(0);
    __builtin_amdgcn_s_setprio(1);
    #pragma unroll
    for (int mi = 0; mi < 4; ++mi)
      #pragma unroll
      for (int ni = 0; ni < 4; ++ni)
        acc0[mi][ni] = __builtin_amdgcn_mfma_f32_16x16x32_bf16(fa[mi], fb[ni], acc0[mi][ni], 0, 0, 0);
    __builtin_amdgcn_s_setprio(0);
    if (last) { asm volatile("s_waitcnt vmcnt(0)" ::: "memory"); }
    else      { asm volatile("s_waitcnt vmcnt(2)" ::: "memory"); }
    __builtin_amdgcn_s_barrier();
    // ---- P1 ----
    #pragma unroll
    for (int mi = 0; mi < 4; ++mi) ga[mi] = *(const s16x8*)(buf + rowA[mi] + 16384 + cp0);
    if (!last) STG(sB, 128, 32768, kb1, nb)
    __builtin_amdgcn_s_barrier();
    asm volatile("s_waitcnt lgkmcnt(0)" ::: "memory");
    __builtin_amdgcn_sched_barrier(0);
    __builtin_amdgcn_s_setprio(1);
    #pragma unroll
    for (int mi = 0; mi < 4; ++mi)
      #pragma unroll
      for (int ni = 0; ni < 4; ++ni)
        acc1[mi][ni] = __builtin_amdgcn_mfma_f32_16x16x32_bf16(ga[mi], fb[ni], acc1[mi][ni], 0, 0, 0);
    __builtin_amdgcn_s_setprio(0);
    __builtin_amdgcn_s_barrier();
    // ---- P2 ----
    #pragma unroll
    for (int mi = 0; mi < 4; ++mi) fa[mi] = *(const s16x8*)(buf + rowA[mi] + cp1);
    #pragma unroll
    for (int ni = 0; ni < 4; ++ni) fb[ni] = *(const s16x8*)(buf + rowB[ni] + cp1);
    if (!last) STG(sA, 0, 0, kb1, nb)
    __builtin_amdgcn_s_barrier();
    asm volatile("s_waitcnt lgkmcnt(0)" ::: "memory");
    __builtin_amdgcn_sched_barrier(0);
    __builtin_amdgcn_s_setprio(1);
    #pragma unroll
    for (int mi = 0; mi < 4; ++mi)
      #pragma unroll
      for (int ni = 0; ni < 4; ++ni)
        acc0[mi][ni] = __builtin_amdgcn_mfma_f32_16x16x32_bf16(fa[mi], fb[ni], acc0[mi][ni], 0, 0, 0);
    __builtin_amdgcn_s_setprio(0);
    __builtin_amdgcn_s_barrier();
    // ---- P3 ----
    #pragma unroll
    for (int mi = 0; mi < 4; ++mi) ga[mi] = *(const s16x8*)(buf + rowA[mi] + 16384 + cp1);
    if (!last) STG(sA, 128, 0, kb1, nb)
    __builtin_amdgcn_s_barrier();
    asm volatile("s_waitcnt lgkmcnt(0)" ::: "memory");
    __builtin_amdgcn_sched_barrier(0);
    __builtin_amdgcn_s_setprio(1);
    #pragma unroll
    for (int mi = 0; mi < 4; ++mi)
      #pragma unroll
      for (int ni = 0; ni < 4; ++ni)
        acc1[mi][ni] = __builtin_amdgcn_mfma_f32_16x16x32_bf16(ga[mi], fb[ni], acc1[mi][ni], 0, 0, 0);
    __builtin_amdgcn_s_setprio(0);
    if (!last) { asm volatile("s_waitcnt vmcnt(2)" ::: "memory"); }
    __builtin_amdgcn_s_barrier();
  }
#undef STG

  if (EPI == 0) {
    const int tensor = (int)(brow0 >> 10);
    if (tensor == 2) {
      __syncthreads();
      u16* wlds = lds + wid*4224;
      const int hbase = (int)((brow0 + wn*64) & 1023);
      const int head = hbase >> 6;
      #pragma unroll
      for (int ph = 0; ph < 2; ++ph) {
        const long grow0 = arow0 + ph*128 + wm*64;
        const int b = (int)(grow0 >> 12), tok0r = (int)(grow0 & 4095);
        #pragma unroll
        for (int mi = 0; mi < 4; ++mi)
          #pragma unroll
          for (int ni = 0; ni < 4; ++ni) {
            const float bv = bias[brow0 + wn*64 + ni*16 + c];
            const f32x4 a = ph ? acc1[mi][ni] : acc0[mi][ni];
            #pragma unroll
            for (int r = 0; r < 4; ++r)
              wlds[(mi*16 + g*4 + r)*66 + ni*16 + c] = f2b(a[r] + bv);
          }
        asm volatile("s_waitcnt lgkmcnt(0)" ::: "memory");
        u16* vbase = outV + (((long)b*NH + head)*DH)*NTOK + tok0r;
        #pragma unroll
        for (int j = 0; j < 8; ++j) {
          const int d = j*8 + (lane >> 3);
          const int tk = (lane & 7)*8;
          s16x8 vv;
          #pragma unroll
          for (int s2 = 0; s2 < 8; ++s2) vv[s2] = (short)wlds[(tk + s2)*66 + d];
          *(s16x8*)(vbase + (long)d*NTOK + tk) = vv;
        }
        asm volatile("s_waitcnt lgkmcnt(0)" ::: "memory");
      }
    } else {
      u16* dst = (tensor == 0) ? outQ : outK;
      const float mul = (tensor == 0) ? 0.125f : 1.0f;
      #pragma unroll
      for (int ph = 0; ph < 2; ++ph)
        #pragma unroll
        for (int mi = 0; mi < 4; ++mi) {
          const int rowb = ph*128 + wm*64 + mi*16 + g*4;
          #pragma unroll
          for (int ni = 0; ni < 4; ++ni) {
            const long gcol = brow0 + wn*64 + ni*16 + c;
            const int c2 = (int)(gcol & 1023);
            const int head = c2 >> 6, dh = c2 & 63;
            const float bv = bias[gcol];
            const f32x4 a = ph ? acc1[mi][ni] : acc0[mi][ni];
            #pragma unroll
            for (int r = 0; r < 4; ++r) {
              const long grow = arow0 + rowb + r;
              const int b = (int)(grow >> 12), tok = (int)(grow & 4095);
              dst[(((long)b*NH + head)*NTOK + tok)*DH + dh] = f2b((a[r] + bv)*mul);
            }
          }
        }
    }
  } else {
    #pragma unroll
    for (int ph = 0; ph < 2; ++ph)
      #pragma unroll
      for (int mi = 0; mi < 4; ++mi) {
        const int rowb = ph*128 + wm*64 + mi*16 + g*4;
        #pragma unroll
        for (int ni = 0; ni < 4; ++ni) {
          const long gcol = brow0 + wn*64 + ni*16 + c;
          const float bv = bias[gcol];
          const f32x4 a = ph ? acc1[mi][ni] : acc0[mi][ni];
          #pragma unroll
          for (int r = 0; r < 4; ++r) {
            const long grow = arow0 + rowb + r;
            outF[grow*N + gcol] = a[r] + bv;
          }
        }
      }
  }
}

// ---------------- fp32 LDS 64x64 matmul helpers ----------------
#define PST 68
static __device__ __forceinline__ void mm_nn8(const float* A, const float* B, float* C, int t) {
  const int lane = t & 63, j0 = (t >> 6) << 3;
  float acc[8];
  #pragma unroll
  for (int j = 0; j < 8; ++j) acc[j] = 0.f;
  for (int k = 0; k < 64; k += 4) {
    const f32x4 a4 = *(const f32x4*)&A[lane*PST + k];
    #pragma unroll
    for (int dk = 0; dk < 4; ++dk) {
      const float a = a4[dk];
      const float* br = &B[(k + dk)*PST + j0];
      const f32x4 b0 = *(const f32x4*)(br);
      const f32x4 b1 = *(const f32x4*)(br + 4);
      #pragma unroll
      for (int qq = 0; qq < 4; ++qq) { acc[qq] += a*b0[qq]; acc[4+qq] += a*b1[qq]; }
    }
  }
  #pragma unroll
  for (int j = 0; j < 8; ++j) C[lane*PST + j0 + j] = acc[j];
}
static __device__ __forceinline__ void mm_nt8(const float* A, const float* B, float* C, int t) {
  const int lane = t & 63, j0 = (t >> 6) << 3;
  float acc[8];
  #pragma unroll
  for (int j = 0; j < 8; ++j) acc[j] = 0.f;
  for (int k = 0; k < 64; k += 4) {
    const f32x4 a4 = *(const f32x4*)&A[lane*PST + k];
    #pragma unroll
    for (int jj = 0; jj < 8; ++jj) {
      const f32x4 b4 = *(const f32x4*)&B[(j0 + jj)*PST + k];
      acc[jj] += a4[0]*b4[0] + a4[1]*b4[1] + a4[2]*b4[2] + a4[3]*b4[3];
    }
  }
  #pragma unroll
  for (int j = 0; j < 8; ++j) C[lane*PST + j0 + j] = acc[j];
}
static __device__ __forceinline__ void mm_nn4(const float* A, const float* B, float* C, int t) {
  const int lane = t & 63, j0 = (t >> 6) << 2;
  float acc[4] = {0.f, 0.f, 0.f, 0.f};
  for (int k = 0; k < 64; k += 4) {
    const f32x4 a4 = *(const f32x4*)&A[lane*PST + k];
    #pragma unroll
    for (int dk = 0; dk < 4; ++dk) {
      const f32x4 b0 = *(const f32x4*)&B[(k + dk)*PST + j0];
      #pragma unroll
      for (int q = 0; q < 4; ++q) acc[q] += a4[dk]*b0[q];
    }
  }
  #pragma unroll
  for (int j = 0; j < 4; ++j) C[lane*PST + j0 + j] = acc[j];
}

// ---------------- merged: pinv (blocks 0..63) | attn3v partials (blocks 64..575), 512 thr ----------------
__global__ __launch_bounds__(512) void k_pa(const float* __restrict__ qlf, const float* __restrict__ klf,
                                            float* __restrict__ a2inv,
                                            const u16* __restrict__ qlb, const u16* __restrict__ kk,
                                            const u16* __restrict__ vt,
                                            float* __restrict__ zp, float* __restrict__ sp) {
  __shared__ __align__(16) char smem[87040];
  const int t = threadIdx.x;
  if (blockIdx.x < 64) {
    float* Xb = (float*)smem;
    float* Vb = Xb + 64*PST;
    float* T1 = Vb + 64*PST;
    float* T2 = T1 + 64*PST;
    float* T3 = T2 + 64*PST;
    const int bh = blockIdx.x;
    const float* ql = qlf + (long)bh*4096;
    const float* kl = klf + (long)bh*4096;
    for (int i = t; i < 4096; i += 512) { T1[(i>>6)*PST + (i&63)] = ql[i]; T2[(i>>6)*PST + (i&63)] = kl[i]; }
    __syncthreads();
    mm_nt8(T1, T2, Xb, t);
    __syncthreads();
    if (t < 64) {
      float mx = -1e30f;
      for (int j = 0; j < 64; ++j) mx = fmaxf(mx, Xb[t*PST + j]);
      float s = 0.f;
      for (int j = 0; j < 64; ++j) { const float e = expf(Xb[t*PST + j] - mx); Xb[t*PST + j] = e; s += e; }
      const float inv = 1.0f/s;
      for (int j = 0; j < 64; ++j) Xb[t*PST + j] *= inv;
    }
    __syncthreads();
    for (int i = t; i < 4096; i += 512) { const int r = i>>6, cc = i&63; Vb[r*PST+cc] = Xb[r*PST+cc]; }
    __syncthreads();
    for (int it = 0; it < 6; ++it) {
      mm_nn8(Xb, Vb, T1, t);  __syncthreads();
      for (int i = t; i < 4096; i += 512) { const int r=i>>6, cc=i&63; T2[r*PST+cc] = (r==cc?7.0f:0.0f) - T1[r*PST+cc]; }
      __syncthreads();
      mm_nn8(T1, T2, T3, t);  __syncthreads();
      for (int i = t; i < 4096; i += 512) { const int r=i>>6, cc=i&63; T2[r*PST+cc] = (r==cc?15.0f:0.0f) - T3[r*PST+cc]; }
      __syncthreads();
      mm_nn8(T1, T2, T3, t);  __syncthreads();
      for (int i = t; i < 4096; i += 512) { const int r=i>>6, cc=i&63; T2[r*PST+cc] = (r==cc?13.0f:0.0f) - T3[r*PST+cc]; }
      __syncthreads();
      mm_nn8(Vb, T2, T3, t);  __syncthreads();
      for (int i = t; i < 4096; i += 512) { const int r=i>>6, cc=i&63; Vb[r*PST+cc] = 0.25f*T3[r*PST+cc]; }
      __syncthreads();
    }
    for (int i = t; i < 4096; i += 512) a2inv[(long)bh*4096 + i] = Vb[(i>>6)*PST + (i&63)];
    return;
  }
  float* Zlp = (float*)smem;               // [4][64][64]
  float* Slp = (float*)(smem + 65536);     // [4][64]
  char*  Plb = smem + 66560;               // [4][64][80B]
  const int abid = blockIdx.x - 64;
  const int bh = abid >> 3, qt = abid & 7;
  if (t < 256) {
    const int w = t >> 6, lane = t & 63;
    const int c = lane & 15, g = lane >> 4;
    s16x8 aq[4][2];
    const u16* qlp = qlb + (long)bh*4096;
    #pragma unroll
    for (int mi = 0; mi < 4; ++mi)
      #pragma unroll
      for (int ks = 0; ks < 2; ++ks)
        aq[mi][ks] = ld8(qlp + (mi*16 + c)*64 + ks*32 + g*8);

    f32x4 zacc[4][4] = {};
    float sl[4][4] = {};
    const u16* kp = kk + (long)bh*NTOK*DH;
    const u16* vp = vt + (long)bh*DH*NTOK;
    char* pbase = Plb + w*5120;
    const int tok00 = qt*512 + w*128;

    for (int it = 0; it < 4; ++it) {
      const int t0 = tok00 + it*32;
      f32x4 sacc[4][2] = {};
      s16x8 kb[2][2];
      #pragma unroll
      for (int cg = 0; cg < 2; ++cg)
        #pragma unroll
        for (int ks = 0; ks < 2; ++ks)
          kb[cg][ks] = ld8(kp + (long)(t0 + cg*16 + c)*64 + ks*32 + g*8);
      #pragma unroll
      for (int cg = 0; cg < 2; ++cg)
        #pragma unroll
        for (int ks = 0; ks < 2; ++ks)
          #pragma unroll
          for (int mi = 0; mi < 4; ++mi)
            sacc[mi][cg] = __builtin_amdgcn_mfma_f32_16x16x32_bf16(aq[mi][ks], kb[cg][ks], sacc[mi][cg], 0, 0, 0);
      #pragma unroll
      for (int mi = 0; mi < 4; ++mi)
        #pragma unroll
        for (int r = 0; r < 4; ++r) {
          const int row = mi*16 + g*4 + r;
          const float p0 = __expf(sacc[mi][0][r]);
          const float p1 = __expf(sacc[mi][1][r]);
          sl[mi][r] += p0 + p1;
          char* base = pbase + row*80;
          *(u16*)(base + c*2)      = f2b(p0);
          *(u16*)(base + 32 + c*2) = f2b(p1);
        }
      s16x8 pa[4];
      #pragma unroll
      for (int mi = 0; mi < 4; ++mi) pa[mi] = *(const s16x8*)(pbase + (mi*16 + c)*80 + g*16);
      #pragma unroll
      for (int ni = 0; ni < 4; ++ni) {
        const s16x8 vb = ld8(vp + (long)(ni*16 + c)*NTOK + t0 + g*8);
        #pragma unroll
        for (int mi = 0; mi < 4; ++mi)
          zacc[mi][ni] = __builtin_amdgcn_mfma_f32_16x16x32_bf16(pa[mi], vb, zacc[mi][ni], 0, 0, 0);
      }
    }
    #pragma unroll
    for (int mi = 0; mi < 4; ++mi)
      #pragma unroll
      for (int r = 0; r < 4; ++r) {
        float s = sl[mi][r];
        s += __shfl_xor(s, 1); s += __shfl_xor(s, 2); s += __shfl_xor(s, 4); s += __shfl_xor(s, 8);
        sl[mi][r] = s;
      }
    #pragma unroll
    for (int mi = 0; mi < 4; ++mi)
      #pragma unroll
      for (int ni = 0; ni < 4; ++ni)
        #pragma unroll
        for (int r = 0; r < 4; ++r)
          Zlp[w*4096 + (mi*16 + g*4 + r)*64 + ni*16 + c] = zacc[mi][ni][r];
    if (c == 0)
      #pragma unroll
      for (int mi = 0; mi < 4; ++mi)
        #pragma unroll
        for (int r = 0; r < 4; ++r)
          Slp[w*64 + mi*16 + g*4 + r] = sl[mi][r];
  }
  __syncthreads();
  float* zpp = zp + (long)abid*4096;
  for (int i = t; i < 4096; i += 512)
    zpp[i] = Zlp[i] + Zlp[4096 + i] + Zlp[8192 + i] + Zlp[12288 + i];
  if (t < 64) sp[(long)abid*64 + t] = Slp[t] + Slp[64 + t] + Slp[128 + t] + Slp[192 + t];
}

// ---------------- fused: z-reduce + W2^T = (attn2inv @ z)^T  (bf16 [dh][lm], 1024 thr) ----------------
__global__ __launch_bounds__(1024) void k_w2(const float* __restrict__ a2inv,
                                             const float* __restrict__ zp, const float* __restrict__ sp,
                                             u16* __restrict__ w2t) {
  __shared__ __align__(16) float Ai[64*PST];
  __shared__ __align__(16) float Zi[64*PST];
  __shared__ __align__(16) float Ci[64*PST];
  __shared__ float Ss[64];
  const int bh = blockIdx.x, t = threadIdx.x;
  if (t < 64) {
    float ss = 0.f;
    #pragma unroll
    for (int qt = 0; qt < 8; ++qt) ss += sp[(long)(bh*8 + qt)*64 + t];
    Ss[t] = 1.0f / ss;
  }
  for (int i = t; i < 4096; i += 1024)
    Ai[(i>>6)*PST + (i&63)] = a2inv[(long)bh*4096 + i];
  __syncthreads();
  for (int i = t; i < 4096; i += 1024) {
    float zs = 0.f;
    #pragma unroll
    for (int qt = 0; qt < 8; ++qt) zs += zp[((long)(bh*8 + qt))*4096 + i];
    Zi[(i>>6)*PST + (i&63)] = zs * Ss[i>>6];
  }
  __syncthreads();
  mm_nn4(Ai, Zi, Ci, t);
  __syncthreads();
  for (int i = t; i < 4096; i += 1024) { const int r = i>>6, cc = i&63; w2t[(long)bh*4096 + cc*64 + r] = f2b(Ci[r*PST + cc]); }
}

// ---------------- out_h = softmax(q @ k_l^T) @ W2: 256 blocks, 4 token-tiles/block (r12 best) ----------------
#define P1ST 144
__global__ __launch_bounds__(256) void k_attn1(const u16* __restrict__ q, const u16* __restrict__ klb,
                                               const u16* __restrict__ w2t, u16* __restrict__ ao) {
  __shared__ __align__(16) u16 Pl[4][64][72];
  const int bx = blockIdx.x, bh = bx >> 2, qd = bx & 3;
  const int b = bh >> 4, h = bh & 15;
  const int t = threadIdx.x, w = t >> 6, lane = t & 63;
  const int c = lane & 15, g = lane >> 4;
  const u16* klp = klb + (long)bh*4096;
  const u16* wp  = w2t + (long)bh*4096;
  char* pbase = (char*)&Pl[w][0][0];

  s16x8 kb[4][2], wb[4][2];
  #pragma unroll
  for (int i = 0; i < 4; ++i)
    #pragma unroll
    for (int ks = 0; ks < 2; ++ks) {
      kb[i][ks] = ld8(klp + (i*16 + c)*64 + ks*32 + g*8);
      wb[i][ks] = ld8(wp  + (i*16 + c)*64 + ks*32 + g*8);
    }
  u16* op = ao + (long)b*NTOK*DM + (long)h*64;

  for (int tt = 0; tt < 4; ++tt) {
    const int tok0 = qd*1024 + tt*256 + w*64;
    const u16* qp = q + ((long)bh*NTOK + tok0)*DH;
    s16x8 aq[4][2];
    #pragma unroll
    for (int i = 0; i < 4; ++i)
      #pragma unroll
      for (int ks = 0; ks < 2; ++ks)
        aq[i][ks] = ld8(qp + (long)(i*16 + c)*DH + ks*32 + g*8);
    f32x4 sacc[4][4] = {};
    #pragma unroll
    for (int ks = 0; ks < 2; ++ks)
      #pragma unroll
      for (int mi = 0; mi < 4; ++mi)
        #pragma unroll
        for (int ni = 0; ni < 4; ++ni)
          sacc[mi][ni] = __builtin_amdgcn_mfma_f32_16x16x32_bf16(aq[mi][ks], kb[ni][ks], sacc[mi][ni], 0, 0, 0);

    float rs[4][4];
    #pragma unroll
    for (int mi = 0; mi < 4; ++mi)
      #pragma unroll
      for (int r = 0; r < 4; ++r) {
        const int row = mi*16 + g*4 + r;
        char* base = pbase + row*P1ST;
        float ssum = 0.f;
        #pragma unroll
        for (int ni = 0; ni < 4; ++ni) {
          const float p = __expf(sacc[mi][ni][r]);
          ssum += p;
          *(u16*)(base + (ni*16 + c)*2) = f2b(p);
        }
        ssum += __shfl_xor(ssum, 1); ssum += __shfl_xor(ssum, 2);
        ssum += __shfl_xor(ssum, 4); ssum += __shfl_xor(ssum, 8);
        rs[mi][r] = ssum;
      }
    asm volatile("s_waitcnt lgkmcnt(0)" ::: "memory");   // wave-local store->read ordering (P tile is per-wave)
    s16x8 pa[4][2];
    #pragma unroll
    for (int mi = 0; mi < 4; ++mi)
      #pragma unroll
      for (int ks = 0; ks < 2; ++ks)
        pa[mi][ks] = *(const s16x8*)(pbase + (mi*16 + c)*P1ST + ks*64 + g*16);
    f32x4 oacc[4][4] = {};
    #pragma unroll
    for (int ks = 0; ks < 2; ++ks)
      #pragma unroll
      for (int mi = 0; mi < 4; ++mi)
        #pragma unroll
        for (int ni = 0; ni < 4; ++ni)
          oacc[mi][ni] = __builtin_amdgcn_mfma_f32_16x16x32_bf16(pa[mi][ks], wb[ni][ks], oacc[mi][ni], 0, 0, 0);

    #pragma unroll
    for (int mi = 0; mi < 4; ++mi)
      #pragma unroll
      for (int r = 0; r < 4; ++r) {
        const int tok = tok0 + mi*16 + g*4 + r;
        const float inv = 1.0f / rs[mi][r];
        #pragma unroll
        for (int ni = 0; ni < 4; ++ni)
          op[(long)tok*DM + ni*16 + c] = f2b(oacc[mi][ni][r] * inv);
      }
    asm volatile("s_waitcnt lgkmcnt(0)" ::: "memory");   // P reads drained before next iter overwrites
  }
}

extern "C" void kernel_launch(void* const* d_in, const int* in_sizes, int n_in,
                              void* d_out, int out_size, void* d_ws, size_t ws_size,
                              hipStream_t stream) {
  const float* hs   = (const float*)d_in[0];
  const float* Wqkv = (const float*)d_in[1];
  const float* bqkv = (const float*)d_in[2];
  const float* Wout = (const float*)d_in[3];
  const float* bout = (const float*)d_in[4];
  float* out = (float*)d_out;
  char* w = (char*)d_ws;

  u16*  Xb    = (u16*)(w);                 // 32MB; dead after gemm0
  float* zp   = (float*)(w);               // aliases Xb (written by k_pa after gemm0), 8MB
  float* sp   = (float*)(w + 8388608L);
  u16*  WqkvT = (u16*)(w + 33554432L);
  u16*  WoutT = (u16*)(w + 39845888L);
  u16*  q     = (u16*)(w + 41943040L);
  float* psum = (float*)(w + 41943040L);   // aliases q: consumed by k_lreduce BEFORE gemm0 writes q
  u16*  k     = (u16*)(w + 75497472L);
  float* Xl   = (float*)(w + 109051904L);
  u16*  vt    = (u16*)(w + 142606336L);    // written directly by gemm0's V epilogue
  float* qlf  = (float*)(w + 176160768L);
  float* klf  = (float*)(w + 177209344L);
  u16*  qlb   = (u16*)(w + 178257920L);
  u16*  klb   = (u16*)(w + 178782208L);
  float* a2i  = (float*)(w + 179306496L);
  u16*  w2t   = (u16*)(w + 181403648L);
  u16*  ao    = (u16*)(w + 181927936L);

  k_pre<<<2048, 256, 0, stream>>>(hs, Xb, Xl, Wqkv, WqkvT, Wout, WoutT);
  k_lproj2<<<dim3(8,8,8), 256, 0, stream>>>(Xl, Wqkv, psum);
  k_lreduce<<<2048, 256, 0, stream>>>(psum, bqkv, qlf, klf, qlb, klb);
  k_gemm256<0><<<dim3(64,12), 512, 0, stream>>>(Xb, WqkvT, bqkv, 3072, nullptr, q, k, vt);
  k_pa<<<576, 512, 0, stream>>>(qlf, klf, a2i, qlb, k, vt, zp, sp);
  k_w2<<<64, 1024, 0, stream>>>(a2i, zp, sp, w2t);
  k_attn1<<<256, 256, 0, stream>>>(q, klb, w2t, ao);
  k_gemm256<1><<<dim3(64,4), 512, 0, stream>>>(ao, WoutT, bout, 1024, out, nullptr, nullptr, nullptr);
}